// Round 10
// baseline (1669.084 us; speedup 1.0000x reference)
//
#include <hip/hip_runtime.h>
#include <math.h>

#define NPTS   20001
#define NREAL  20000
#define EPAD   1200000
#define KK     64
#define RADF   0.1125f
#define CHUNK  4096

__device__ __forceinline__ float sgnf(float v){ return v>0.f ? 1.f : (v<0.f ? -1.f : 0.f); }

// ---------------- CSR build (edge_src is sorted; pad edges have dst==NREAL) ----------------
__global__ void k_find_ereal(const int* __restrict__ dst, int* __restrict__ ereal){
  int lo=0, hi=EPAD;
  while(lo<hi){ int mid=(lo+hi)>>1; if(dst[mid]==NREAL) hi=mid; else lo=mid+1; }
  *ereal = lo;
}

__global__ void k_csr(const int* __restrict__ src, const int* __restrict__ erealp,
                      int* __restrict__ row_start){
  int i = blockIdx.x*blockDim.x + threadIdx.x;
  if(i > NPTS) return;
  int E = *erealp;
  int lo=0, hi=E;
  while(lo<hi){ int mid=(lo+hi)>>1; if(src[mid] < i) lo=mid+1; else hi=mid; }
  row_start[i] = lo;
}

__global__ void k_build_f(const float* __restrict__ feats, float* __restrict__ f){
  int idx = blockIdx.x*blockDim.x + threadIdx.x;
  if(idx >= NPTS*13) return;
  int i = idx/13, c = idx - i*13;
  f[idx] = (c==0) ? 1.f : feats[i*12 + (c-1)];
}

// ---------------- per-edge geometry (exact port of ball_to_cube + window) ----------------
__device__ __forceinline__ void edge_geom(float ox, float oy, float oz,
                                          float& win, float& t0, float& t1, float& t2, int& f0p){
  const float eps = 1e-9f;
  float sq = ox*ox + oy*oy + oz*oz;
  float u = 1.f - sq;
  win = fminf(fmaxf(u*u*u, 0.f), 1.f);
  float norm = sqrtf(sq + eps);
  float rxy2 = ox*ox + oy*oy;
  bool polar = (1.25f*oz*oz > rxy2);
  float s_p = sqrtf(3.f*norm/(norm + fabsf(oz) + eps));
  float s_n = norm / sqrtf(rxy2 + eps);
  float s = polar ? s_p : s_n;
  float xc = ox*s, yc = oy*s;
  float zc = polar ? sgnf(oz)*norm : 1.5f*oz;
  if(sq < 1e-12f){ xc = 0.f; yc = 0.f; zc = 0.f; }
  float r = sqrtf(xc*xc + yc*yc + eps);
  bool c1 = fabsf(xc) >= fabsf(yc);
  float xs = (fabsf(xc) < eps) ? eps : xc;
  float ys = (fabsf(yc) < eps) ? eps : yc;
  const float fop = 1.2732395447351628f; // float32(4/pi)
  float a = c1 ? sgnf(xc)*r : sgnf(yc)*r*fop*atanf(xc/ys);
  float b = c1 ? sgnf(xc)*r*fop*atanf(yc/xs) : sgnf(yc)*r;
  if(xc*xc + yc*yc < 1e-12f){ a = 0.f; b = 0.f; }
  float g0 = fminf(fmaxf((a *0.5f+0.5f)*3.f, 0.f), 3.f);
  float g1 = fminf(fmaxf((b *0.5f+0.5f)*3.f, 0.f), 3.f);
  float g2 = fminf(fmaxf((zc*0.5f+0.5f)*3.f, 0.f), 3.f);
  float f00 = floorf(g0), f01 = floorf(g1), f02 = floorf(g2);
  t0 = g0 - f00; t1 = g1 - f01; t2 = g2 - f02;
  f0p = (int)f00 | ((int)f01 << 2) | ((int)f02 << 4);
}

// Staging: 8 win-premultiplied corner weights split per z-parity wave (float4 each, in
// SEPARATE contiguous arrays -> conflict-free) + packed cell ids + dst.
// min(i+1,3) -> (i+1)&3 is exact (clamped corner has t==0 weight), making all 8 cells
// distinct -> batched read/fma/write is race-free.
__device__ __forceinline__ void stage_edge(float win, float t0, float t1, float t2, int f0p,
                                           int d, float4* wA, float4* wB, int4* meta){
  const int i0 = f0p & 3, i1 = (f0p>>2) & 3, i2 = f0p >> 4;
  const int X0 = i0 << 4, X1 = ((i0+1)&3) << 4;
  const int Y0 = i1 << 2, Y1 = ((i1+1)&3) << 2;
  const int Z0 = i2, Z1 = (i2+1) & 3;
  const float wx0 = win*(1.f-t0), wx1 = win*t0;
  const float wy0 = 1.f-t1, wy1 = t1;
  const float wz0 = 1.f-t2, wz1 = t2;
  const float q00 = wx0*wy0, q01 = wx0*wy1, q10 = wx1*wy0, q11 = wx1*wy1;
  const int p0 = Z0 & 1;
  const float zA = p0 ? wz1 : wz0;  const int cA = p0 ? Z1 : Z0;  // wave 0 (even z)
  const float zB = p0 ? wz0 : wz1;  const int cB = p0 ? Z0 : Z1;  // wave 1 (odd z)
  *wA = make_float4(q00*zA, q01*zA, q10*zA, q11*zA);
  *wB = make_float4(q00*zB, q01*zB, q10*zB, q11*zB);
  const int cells0 = (X0|Y0|cA) | ((X0|Y1|cA)<<8) | ((X1|Y0|cA)<<16) | ((X1|Y1|cA)<<24);
  const int cells1 = (X0|Y0|cB) | ((X0|Y1|cB)<<8) | ((X1|Y0|cB)<<16) | ((X1|Y1|cB)<<24);
  *meta = make_int4(cells0, cells1, d, 0);
}

// ------- scatter, channel-split: grid.y sub-blocks of 32 channels each.
// Block = 2 waves (z-parity); within a wave, 2x32-lane slots process TWO edges at once
// (lane = (edge-parity, channel)). Single 8KB B copy per sub-block; batched distinct-cell
// RMW is race-free (parity across waves, channel ownership across lanes, edge-parity slots
// touch different cells' rows only via different edges -> distinct (cell,ch) words per op... 
// slots write different edges' cells: two edges may share a cell+channel word! 
// NOT race-free across slots -> slots must interleave-own edges, and both slots write the
// SAME Bl -> use per-slot z-sub-parity instead: see mapping below (safe: slots share wave,
// execute in lockstep, but RMW of same word by 2 lanes in one instruction loses an update).
// Therefore: slot ownership is folded into the corner dimension: wave w, slot s owns the
// single z-cell of parity w (each edge has exactly ONE z-cell per parity after the split:
// cells {zs} x {X0,X1} x {Y0,Y1} = 4 cells; we give slot 0 the X0 pair and slot 1 the X1
// pair of ITS OWN edge -- different edges can still collide on a word!).
// => Correct resolution: each slot processes edges with j%2==s AND accumulates ALL 4 of its
// corners; a collision requires two lanes in the same instruction targeting the same word:
// lanes differ in channel (c) unless in different slots; cross-slot same word means same
// (cell,channel) with same c => possible. To exclude it, slot s uses a PRIVATE half-row:
// Bl layout [cell][slot][32ch] (64 floats per cell) and the write-out sums the two halves.
// LDS 16KB total. This restores exact privacy with one extra reduction at write-out.
template<int CIN, int RELU, int OUT3>
__global__ __launch_bounds__(128) void k_scatC(
    const float* __restrict__ feat, const float* __restrict__ pos,
    const int* __restrict__ edst, const int* __restrict__ row_start,
    float* __restrict__ B, int node_base,
    const float* __restrict__ W3, float* __restrict__ out)
{
  constexpr int NCH = 32;
  constexpr int BSZ = 64*2*NCH;                 // [cell][slot][ch] = 4096 floats = 16KB
  __shared__ __align__(16) float Bl[BSZ];
  __shared__ __align__(16) float4 g_wA[128];
  __shared__ __align__(16) float4 g_wB[128];
  __shared__ __align__(16) int4   g_meta[128];

  const int tid  = threadIdx.x;
  const int node = node_base + blockIdx.x;
  const int cy   = blockIdx.y * NCH;            // channel offset of this sub-block

  for(int j = tid*4; j < BSZ; j += 512)
    *(float4*)&Bl[j] = make_float4(0.f,0.f,0.f,0.f);

  const int e0 = row_start[node], e1 = row_start[node+1];
  const float px = pos[node*3+0], py = pos[node*3+1], pz = pos[node*3+2];

  const int wv   = tid >> 6;        // z-parity owned by this wave
  const int lane = tid & 63;
  const int es   = lane >> 5;       // edge-parity slot
  const int c    = lane & 31;       // channel within sub-block
  float* Bp = Bl + es*NCH;          // slot-private half of each cell row
  __syncthreads();

  for(int eb = e0; eb < e1; eb += 128){
    const int m = min(128, e1 - eb);
    if(tid < m){
      const int d = edst[eb + tid];
      float ox = (pos[d*3+0]-px)/RADF;
      float oy = (pos[d*3+1]-py)/RADF;
      float oz = (pos[d*3+2]-pz)/RADF;
      float win, t0, t1, t2; int f0p;
      edge_geom(ox, oy, oz, win, t0, t1, t2, f0p);
      stage_edge(win, t0, t1, t2, f0p, d, &g_wA[tid], &g_wB[tid], &g_meta[tid]);
    }
    __syncthreads();
    #pragma unroll 2
    for(int base = 0; base < m; base += 2){
      const int j = base + es;
      const bool ok = (j < m);
      const int jc = ok ? j : 0;
      const int4 mt = g_meta[jc];
      const float4 w4 = wv ? g_wB[jc] : g_wA[jc];
      float v = feat[(size_t)mt.z*CIN + cy + c];
      if(RELU) v = fmaxf(v, 0.f);
      const int cp = wv ? mt.y : mt.x;
      const int b0 = (( cp        & 255) << 6) + c;   // cell*64 + slot*32 + c (slot in Bp)
      const int b1 = (((cp >> 8)  & 255) << 6) + c;
      const int b2 = (((cp >> 16) & 255) << 6) + c;
      const int b3 = ((((unsigned)cp) >> 24) << 6) + c;
      if(ok){
        float o0 = Bp[b0], o1 = Bp[b1], o2 = Bp[b2], o3 = Bp[b3];
        o0 = fmaf(w4.x, v, o0); o1 = fmaf(w4.y, v, o1);
        o2 = fmaf(w4.z, v, o2); o3 = fmaf(w4.w, v, o3);
        Bp[b0] = o0; Bp[b1] = o1; Bp[b2] = o2; Bp[b3] = o3;
      }
    }
    __syncthreads();
  }

  if(!OUT3){
    // write-out: sum the two slot halves; B[node][cell][CIN] layout
    float* Bg = B + (size_t)blockIdx.x*(64*CIN) + cy;
    for(int j = tid*4; j < 64*NCH; j += 512){
      const int cell = j >> 5, cc = j & 31;
      float4 a = *(const float4*)&Bl[(cell<<6) + cc];
      const float4 t = *(const float4*)&Bl[(cell<<6) + NCH + cc];
      a.x += t.x; a.y += t.y; a.z += t.z; a.w += t.w;
      *(float4*)&Bg[cell*CIN + cc] = a;
    }
  } else {
    // fused cout=3 GEMV over this sub-block's channels; atomicAdd into out
    float s0=0.f, s1=0.f, s2=0.f;
    for(int j = tid; j < 64*NCH; j += 128){
      const int cell = j >> 5, cc = j & 31;
      const float v = Bl[(cell<<6) + cc] + Bl[(cell<<6) + NCH + cc];
      const int kidx = (cell*64 + cy + cc)*3;
      s0 = fmaf(v, W3[kidx+0], s0);
      s1 = fmaf(v, W3[kidx+1], s1);
      s2 = fmaf(v, W3[kidx+2], s2);
    }
    float* r0 = (float*)g_wA;   // reuse staging LDS for reduction
    float* r1 = r0 + 128;
    float* r2 = r1 + 128;
    r0[tid]=s0; r1[tid]=s1; r2[tid]=s2;
    __syncthreads();
    for(int st = 64; st > 0; st >>= 1){
      if(tid < st){ r0[tid]+=r0[tid+st]; r1[tid]+=r1[tid+st]; r2[tid]+=r2[tid+st]; }
      __syncthreads();
    }
    if(tid == 0 && node < NREAL){
      atomicAdd(&out[node*3+0], r0[0]*(1.f/128.f));
      atomicAdd(&out[node*3+1], r1[0]*(1.f/128.f));
      atomicAdd(&out[node*3+2], r2[0]*(1.f/128.f));
    }
  }
}

// ---------------- scatter CIN=13: 4 edge-slots/wave, 1 channel/lane, z-parity waves -------
__global__ __launch_bounds__(128) void k_scat13(
    const float* __restrict__ feat, const float* __restrict__ pos,
    const int* __restrict__ edst, const int* __restrict__ row_start,
    float* __restrict__ B, int node_base)
{
  constexpr int CIN = 13, BSZ = KK*CIN, ESW = 4;
  constexpr int CSTRIDE = BSZ + 8;
  __shared__ __align__(16) float Bl[ESW*CSTRIDE];
  __shared__ __align__(16) float4 g_wA[128];
  __shared__ __align__(16) float4 g_wB[128];
  __shared__ __align__(16) int4   g_meta[128];

  const int tid  = threadIdx.x;
  const int node = node_base + blockIdx.x;

  for(int j = tid; j < ESW*CSTRIDE; j += 128) Bl[j] = 0.f;

  const int e0 = row_start[node], e1 = row_start[node+1];
  const float px = pos[node*3+0], py = pos[node*3+1], pz = pos[node*3+2];

  const int wv   = tid >> 6;
  const int lane = tid & 63;
  const int slot = lane >> 4;
  const int c    = lane & 15;
  const bool act = (c < CIN);
  float* Bp = Bl + slot*CSTRIDE;
  __syncthreads();

  for(int eb = e0; eb < e1; eb += 128){
    const int m = min(128, e1 - eb);
    if(tid < m){
      const int d = edst[eb + tid];
      float ox = (pos[d*3+0]-px)/RADF;
      float oy = (pos[d*3+1]-py)/RADF;
      float oz = (pos[d*3+2]-pz)/RADF;
      float win, t0, t1, t2; int f0p;
      edge_geom(ox, oy, oz, win, t0, t1, t2, f0p);
      stage_edge(win, t0, t1, t2, f0p, d, &g_wA[tid], &g_wB[tid], &g_meta[tid]);
    }
    __syncthreads();
    if(act){
      for(int j = slot; j < m; j += ESW){
        const int4 mt = g_meta[j];
        const float4 w4 = wv ? g_wB[j] : g_wA[j];
        float v = feat[(size_t)mt.z*CIN + c];
        const int cp = wv ? mt.y : mt.x;
        const int b0 = ( cp        & 255)*CIN + c;
        const int b1 = ((cp >> 8)  & 255)*CIN + c;
        const int b2 = ((cp >> 16) & 255)*CIN + c;
        const int b3 = (((unsigned)cp) >> 24)*CIN + c;
        float o0 = Bp[b0], o1 = Bp[b1], o2 = Bp[b2], o3 = Bp[b3];
        o0 = fmaf(w4.x, v, o0); o1 = fmaf(w4.y, v, o1);
        o2 = fmaf(w4.z, v, o2); o3 = fmaf(w4.w, v, o3);
        Bp[b0] = o0; Bp[b1] = o1; Bp[b2] = o2; Bp[b3] = o3;
      }
    }
    __syncthreads();
  }

  float* Bg = B + (size_t)blockIdx.x*BSZ;
  for(int j = tid*4; j < BSZ; j += 512){
    float4 a = *(const float4*)&Bl[j];
    #pragma unroll
    for(int k = 1; k < ESW; ++k){
      const float4 t = *(const float4*)&Bl[k*CSTRIDE + j];
      a.x += t.x; a.y += t.y; a.z += t.z; a.w += t.w;
    }
    *(float4*)&Bg[j] = a;
  }
}

// ---- GEMM, no atomics: P[s][node][64] = sum_{k in split s} A[row,k]*W[k,o]
__global__ __launch_bounds__(256) void k_gemm2(
    const float* __restrict__ A, const float* __restrict__ W,
    float* __restrict__ P, int M, int Kd, int node_base, int ktiles_per)
{
  __shared__ __align__(16) float As[16][68];   // [k][row]
  __shared__ __align__(16) float Ws[16][64];   // [k][col]
  const int tid = threadIdx.x;
  const int mbase = blockIdx.x * 64;
  const int s = blockIdx.y;
  const int kt0 = s * ktiles_per * 16;
  const int kt1 = min(Kd, kt0 + ktiles_per*16);
  const int ty = tid >> 4, tx = tid & 15;
  const int arow = tid >> 2, ako = (tid & 3) * 4;
  const int wk = tid >> 4,  wc = (tid & 15) * 4;

  float acc[4][4];
  #pragma unroll
  for(int i=0;i<4;++i)
    #pragma unroll
    for(int j=0;j<4;++j) acc[i][j] = 0.f;

  for(int kt = kt0; kt < kt1; kt += 16){
    float4 av = make_float4(0.f,0.f,0.f,0.f);
    const int grow = mbase + arow;
    if(grow < M) av = *(const float4*)(A + (size_t)grow*Kd + kt + ako);
    const float4 wv = *(const float4*)(W + (size_t)(kt + wk)*64 + wc);
    As[ako+0][arow]=av.x; As[ako+1][arow]=av.y; As[ako+2][arow]=av.z; As[ako+3][arow]=av.w;
    *(float4*)&Ws[wk][wc] = wv;
    __syncthreads();
    #pragma unroll
    for(int kk = 0; kk < 16; ++kk){
      const float4 a = *(const float4*)&As[kk][ty*4];
      const float4 b = *(const float4*)&Ws[kk][tx*4];
      const float aa[4] = {a.x,a.y,a.z,a.w};
      const float bb[4] = {b.x,b.y,b.z,b.w};
      #pragma unroll
      for(int i=0;i<4;++i)
        #pragma unroll
        for(int j=0;j<4;++j) acc[i][j] = fmaf(aa[i], bb[j], acc[i][j]);
    }
    __syncthreads();
  }

  #pragma unroll
  for(int i=0;i<4;++i){
    const int row = mbase + ty*4 + i;
    if(row < M)
      *(float4*)(P + ((size_t)s*NPTS + node_base + row)*64 + tx*4) = *(float4*)&acc[i][0];
  }
}

// ---- combine partials: x[node*ldout+colofs+o] += sum_s P[s][node][o]
template<int S>
__global__ void k_combine(const float* __restrict__ P, float* __restrict__ x,
                          int ldout, int colofs)
{
  int idx = blockIdx.x*blockDim.x + threadIdx.x;
  if(idx >= NPTS*16) return;
  int node = idx >> 4, c4 = (idx & 15) * 4;
  float4 s = *(const float4*)(P + (size_t)node*64 + c4);
  #pragma unroll
  for(int k=1;k<S;++k){
    float4 t = *(const float4*)(P + ((size_t)k*NPTS + node)*64 + c4);
    s.x+=t.x; s.y+=t.y; s.z+=t.z; s.w+=t.w;
  }
  float* xp = x + (size_t)node*ldout + colofs + c4;
  float4 o = *(float4*)xp;
  o.x+=s.x; o.y+=s.y; o.z+=s.z; o.w+=s.w;
  *(float4*)xp = o;
}

// ---------------- dense paths ----------------
__global__ void k_dense0(const float* __restrict__ f, const float* __restrict__ dW,
                         const float* __restrict__ db, const float* __restrict__ cb0,
                         float* __restrict__ out)
{
  int idx = blockIdx.x*blockDim.x + threadIdx.x;
  if(idx >= NPTS*96) return;
  int i = idx/96, c = idx - i*96;
  if(c < 64){ out[idx] = cb0[c]; return; }
  int o = c - 64;
  float s = db[o];
  const float* row = f + (size_t)i*13;
  #pragma unroll
  for(int j=0;j<13;++j) s = fmaf(row[j], dW[j*32+o], s);
  out[idx] = s;
}

__global__ void k_dense(const float* __restrict__ in, int cin,
                        const float* __restrict__ dW, const float* __restrict__ db,
                        const float* __restrict__ cb, const float* __restrict__ resid,
                        float* __restrict__ out)
{
  int idx = blockIdx.x*blockDim.x + threadIdx.x;
  if(idx >= NPTS*64) return;
  int i = idx >> 6, o = idx & 63;
  float s = db[o] + cb[o];
  if(resid) s += resid[idx];
  const float* row = in + (size_t)i*cin;
  for(int c=0;c<cin;++c) s = fmaf(fmaxf(row[c],0.f), dW[c*64+o], s);
  out[idx] = s;
}

__global__ void k_dense3(const float* __restrict__ x2, const float* __restrict__ dW,
                         const float* __restrict__ db, const float* __restrict__ cb,
                         float* __restrict__ out)
{
  int idx = blockIdx.x*blockDim.x + threadIdx.x;
  if(idx >= NREAL*3) return;
  int i = idx/3, o = idx - i*3;
  float s = db[o] + cb[o];
  const float* row = x2 + (size_t)i*64;
  for(int c=0;c<64;++c) s = fmaf(fmaxf(row[c],0.f), dW[c*3+o], s);
  out[idx] = s * (1.f/128.f);
}

// ---------------- host ----------------
static inline size_t alup(size_t x){ return (x + 255) & ~(size_t)255; }

static inline int calc_rows(size_t bcap, int cin){
  size_t perrow = (size_t)KK * cin * 4;
  size_t r = (perrow > 0) ? bcap / perrow : 0;
  if(r >= (size_t)CHUNK) return CHUNK;
  r = (r / 128) * 128;
  if(r < 128) r = 128;
  return (int)r;
}

extern "C" void kernel_launch(void* const* d_in, const int* in_sizes, int n_in,
                              void* d_out, int out_size, void* d_ws, size_t ws_size,
                              hipStream_t stream)
{
  const float* pos   = (const float*)d_in[0];
  const float* feats = (const float*)d_in[1];
  const int*   esrc  = (const int*)d_in[2];
  const int*   edst  = (const int*)d_in[3];
  const float* c0w = (const float*)d_in[4];
  const float* c0b = (const float*)d_in[5];
  const float* d0w = (const float*)d_in[6];
  const float* d0b = (const float*)d_in[7];
  const float* c1w = (const float*)d_in[8];
  const float* c1b = (const float*)d_in[9];
  const float* d1w = (const float*)d_in[10];
  const float* d1b = (const float*)d_in[11];
  const float* c2w = (const float*)d_in[12];
  const float* c2b = (const float*)d_in[13];
  const float* d2w = (const float*)d_in[14];
  const float* d2b = (const float*)d_in[15];
  const float* c3w = (const float*)d_in[16];
  const float* c3b = (const float*)d_in[17];
  const float* d3w = (const float*)d_in[18];
  const float* d3b = (const float*)d_in[19];
  float* out = (float*)d_out;

  char* w = (char*)d_ws;
  size_t off = 0;
  float* f  = (float*)(w+off); off += alup((size_t)NPTS*13*4);
  float* x0 = (float*)(w+off); off += alup((size_t)NPTS*96*4);
  float* x1 = (float*)(w+off); off += alup((size_t)NPTS*64*4);
  float* x2 = (float*)(w+off); off += alup((size_t)NPTS*64*4);
  int* row_start = (int*)(w+off); off += alup((size_t)(NPTS+1)*4);
  int* ereal = (int*)(w+off);     off += alup(16);
  float* P  = (float*)(w+off); off += alup((size_t)16*NPTS*64*4);  // split-K partials (S<=16)
  float* B = (float*)(w+off);
  size_t bcap = (ws_size > off) ? (ws_size - off) : 0;

  k_find_ereal<<<1,1,0,stream>>>(edst, ereal);
  k_csr<<<(NPTS+1+255)/256,256,0,stream>>>(esrc, ereal, row_start);
  k_build_f<<<(NPTS*13+255)/256,256,0,stream>>>(feats, f);

  // ---- layer 0: x0[:,0:64] = cconv0(f)+c0b ; x0[:,64:96] = f@d0w+d0b
  k_dense0<<<(NPTS*96+255)/256,256,0,stream>>>(f, d0w, d0b, c0b, x0);
  {
    int rows = calc_rows(bcap, 13);
    for(int base = 0; base < NPTS; base += rows){
      int m = (NPTS - base < rows) ? (NPTS - base) : rows;
      k_scat13<<<m,128,0,stream>>>(f, pos, edst, row_start, B, base);
      k_gemm2<<<dim3((m+63)/64, 8),256,0,stream>>>(B, c0w, P, m, 832, base, 7);
    }
    k_combine<8><<<(NPTS*16+255)/256,256,0,stream>>>(P, x0, 96, 0);
  }

  // ---- layer 1: x1 = cconv1(relu(x0)) + relu(x0)@d1w + d1b + c1b
  k_dense<<<(NPTS*64+255)/256,256,0,stream>>>(x0, 96, d1w, d1b, c1b, nullptr, x1);
  {
    int rows = calc_rows(bcap, 96);
    for(int base = 0; base < NPTS; base += rows){
      int m = (NPTS - base < rows) ? (NPTS - base) : rows;
      k_scatC<96,1,0><<<dim3(m,3),128,0,stream>>>(x0, pos, edst, row_start, B, base, nullptr, nullptr);
      k_gemm2<<<dim3((m+63)/64, 16),256,0,stream>>>(B, c1w, P, m, 6144, base, 24);
    }
    k_combine<16><<<(NPTS*16+255)/256,256,0,stream>>>(P, x1, 64, 0);
  }

  // ---- layer 2: x2 = cconv2(relu(x1)) + relu(x1)@d2w + d2b + c2b + x1 (residual)
  k_dense<<<(NPTS*64+255)/256,256,0,stream>>>(x1, 64, d2w, d2b, c2b, x1, x2);
  {
    int rows = calc_rows(bcap, 64);
    for(int base = 0; base < NPTS; base += rows){
      int m = (NPTS - base < rows) ? (NPTS - base) : rows;
      k_scatC<64,1,0><<<dim3(m,2),128,0,stream>>>(x1, pos, edst, row_start, B, base, nullptr, nullptr);
      k_gemm2<<<dim3((m+63)/64, 16),256,0,stream>>>(B, c2w, P, m, 4096, base, 16);
    }
    k_combine<16><<<(NPTS*16+255)/256,256,0,stream>>>(P, x2, 64, 0);
  }

  // ---- layer 3 (fused): out = dense3 part, then scatter adds conv3 GEMV via atomics
  k_dense3<<<(NREAL*3+255)/256,256,0,stream>>>(x2, d3w, d3b, c3b, out);
  k_scatC<64,1,1><<<dim3(NPTS,2),128,0,stream>>>(x2, pos, edst, row_start, nullptr, 0, c3w, out);
}

// Round 12
// 1500.799 us; speedup vs baseline: 1.1121x; 1.1121x over previous
//
#include <hip/hip_runtime.h>
#include <math.h>

#define NPTS   20001
#define NREAL  20000
#define EPAD   1200000
#define KK     64
#define RADF   0.1125f

__device__ __forceinline__ float sgnf(float v){ return v>0.f ? 1.f : (v<0.f ? -1.f : 0.f); }

// ---------------- CSR build (edge_src is sorted; pad edges have dst==NREAL) ----------------
__global__ void k_find_ereal(const int* __restrict__ dst, int* __restrict__ ereal){
  int lo=0, hi=EPAD;
  while(lo<hi){ int mid=(lo+hi)>>1; if(dst[mid]==NREAL) hi=mid; else lo=mid+1; }
  *ereal = lo;
}

__global__ void k_csr(const int* __restrict__ src, const int* __restrict__ erealp,
                      int* __restrict__ row_start){
  int i = blockIdx.x*blockDim.x + threadIdx.x;
  if(i > NPTS) return;
  int E = *erealp;
  int lo=0, hi=E;
  while(lo<hi){ int mid=(lo+hi)>>1; if(src[mid] < i) lo=mid+1; else hi=mid; }
  row_start[i] = lo;
}

__global__ void k_build_f(const float* __restrict__ feats, float* __restrict__ f){
  int idx = blockIdx.x*blockDim.x + threadIdx.x;
  if(idx >= NPTS*13) return;
  int i = idx/13, c = idx - i*13;
  f[idx] = (c==0) ? 1.f : feats[i*12 + (c-1)];
}

// ---------------- per-edge geometry (exact port of ball_to_cube + window) ----------------
__device__ __forceinline__ void edge_geom(float ox, float oy, float oz,
                                          float& win, float& t0, float& t1, float& t2, int& f0p){
  const float eps = 1e-9f;
  float sq = ox*ox + oy*oy + oz*oz;
  float u = 1.f - sq;
  win = fminf(fmaxf(u*u*u, 0.f), 1.f);
  float norm = sqrtf(sq + eps);
  float rxy2 = ox*ox + oy*oy;
  bool polar = (1.25f*oz*oz > rxy2);
  float s_p = sqrtf(3.f*norm/(norm + fabsf(oz) + eps));
  float s_n = norm / sqrtf(rxy2 + eps);
  float s = polar ? s_p : s_n;
  float xc = ox*s, yc = oy*s;
  float zc = polar ? sgnf(oz)*norm : 1.5f*oz;
  if(sq < 1e-12f){ xc = 0.f; yc = 0.f; zc = 0.f; }
  float r = sqrtf(xc*xc + yc*yc + eps);
  bool c1 = fabsf(xc) >= fabsf(yc);
  float xs = (fabsf(xc) < eps) ? eps : xc;
  float ys = (fabsf(yc) < eps) ? eps : yc;
  const float fop = 1.2732395447351628f; // float32(4/pi)
  float a = c1 ? sgnf(xc)*r : sgnf(yc)*r*fop*atanf(xc/ys);
  float b = c1 ? sgnf(xc)*r*fop*atanf(yc/xs) : sgnf(yc)*r;
  if(xc*xc + yc*yc < 1e-12f){ a = 0.f; b = 0.f; }
  float g0 = fminf(fmaxf((a *0.5f+0.5f)*3.f, 0.f), 3.f);
  float g1 = fminf(fmaxf((b *0.5f+0.5f)*3.f, 0.f), 3.f);
  float g2 = fminf(fmaxf((zc*0.5f+0.5f)*3.f, 0.f), 3.f);
  float f00 = floorf(g0), f01 = floorf(g1), f02 = floorf(g2);
  t0 = g0 - f00; t1 = g1 - f01; t2 = g2 - f02;
  f0p = (int)f00 | ((int)f01 << 2) | ((int)f02 << 4);
}

// ---- k_geom: per-edge staged data, computed ONCE (shared by all 4 scatter layers).
// gw[e]  = win-premultiplied xy-quad weights {q00,q01,q10,q11}
// gmz[e] = {bits(zA), cells0, cells1, dst}; zB = 1-zA (wz0+wz1==1 exactly).
// min(i+1,3) -> (i+1)&3 is exact (clamped corner has t==0 weight): all 8 cells distinct ->
// batched read/fma/write in the scatters is race-free; parity-p cells owned by wave p.
__global__ __launch_bounds__(256) void k_geom(const float* __restrict__ pos,
    const int* __restrict__ esrc, const int* __restrict__ edst,
    float4* __restrict__ gw, int4* __restrict__ gmz)
{
  int e = blockIdx.x*blockDim.x + threadIdx.x;
  if(e >= EPAD) return;
  const int sn = esrc[e], d = edst[e];
  const float ox = (pos[d*3+0]-pos[sn*3+0])/RADF;
  const float oy = (pos[d*3+1]-pos[sn*3+1])/RADF;
  const float oz = (pos[d*3+2]-pos[sn*3+2])/RADF;
  float win, t0, t1, t2; int f0p;
  edge_geom(ox, oy, oz, win, t0, t1, t2, f0p);
  const int i0 = f0p & 3, i1 = (f0p>>2) & 3, i2 = f0p >> 4;
  const int X0 = i0 << 4, X1 = ((i0+1)&3) << 4;
  const int Y0 = i1 << 2, Y1 = ((i1+1)&3) << 2;
  const int Z0 = i2, Z1 = (i2+1) & 3;
  const float wx0 = win*(1.f-t0), wx1 = win*t0;
  const float wy0 = 1.f-t1, wy1 = t1;
  const float wz0 = 1.f-t2, wz1 = t2;
  gw[e] = make_float4(wx0*wy0, wx0*wy1, wx1*wy0, wx1*wy1);
  const int p0 = Z0 & 1;
  const float zA = p0 ? wz1 : wz0;                  // weight for parity-0 (even z) cell
  const int   cA = p0 ? Z1 : Z0;                    // even-z cell
  const int   cB = p0 ? Z0 : Z1;                    // odd-z cell
  const int cells0 = (X0|Y0|cA) | ((X0|Y1|cA)<<8) | ((X1|Y0|cA)<<16) | ((X1|Y1|cA)<<24);
  const int cells1 = (X0|Y0|cB) | ((X0|Y1|cB)<<8) | ((X1|Y0|cB)<<16) | ((X1|Y1|cB)<<24);
  gmz[e] = make_int4(__float_as_int(zA), cells0, cells1, d);
}

// ------- scatter CIN=64: 2 waves (z-parity), lane = channel, barrier-free inner loop.
// Staged data read from global (broadcast address, L1/L2 resident). Single 16KB B copy.
// OUT3=1: fused cout=3 GEMV epilogue (layer 3).
template<int RELU, int OUT3>
__global__ __launch_bounds__(128) void k_scat64(
    const float* __restrict__ feat, const float4* __restrict__ gw,
    const int4* __restrict__ gmz, const int* __restrict__ row_start,
    float* __restrict__ B, int node_base,
    const float* __restrict__ W3, float* __restrict__ out)
{
  constexpr int BSZ = 64*64;
  __shared__ __align__(16) float Bl[BSZ];
  __shared__ float red[OUT3 ? 384 : 4];
  const int tid  = threadIdx.x;
  const int node = node_base + blockIdx.x;

  for(int j = tid*4; j < BSZ; j += 512)
    *(float4*)&Bl[j] = make_float4(0.f,0.f,0.f,0.f);

  const int e0 = row_start[node], e1 = row_start[node+1];
  const int wv = tid >> 6;          // z-parity owned by this wave
  const int c  = tid & 63;          // owned channel
  __syncthreads();

  #pragma unroll 2
  for(int e = e0; e < e1; ++e){
    const float4 q  = gw[e];
    const int4   md = gmz[e];
    const float zA = __int_as_float(md.x);
    const float z  = wv ? (1.f - zA) : zA;
    const int   cp = wv ? md.z : md.y;
    float v = feat[(size_t)md.w*64 + c];
    if(RELU) v = fmaxf(v, 0.f);
    v *= z;
    const int b0 = (( cp        & 255) << 6) + c;
    const int b1 = (((cp >> 8)  & 255) << 6) + c;
    const int b2 = (((cp >> 16) & 255) << 6) + c;
    const int b3 = ((((unsigned)cp) >> 24) << 6) + c;
    float o0 = Bl[b0], o1 = Bl[b1], o2 = Bl[b2], o3 = Bl[b3];
    o0 = fmaf(q.x, v, o0); o1 = fmaf(q.y, v, o1);
    o2 = fmaf(q.z, v, o2); o3 = fmaf(q.w, v, o3);
    Bl[b0] = o0; Bl[b1] = o1; Bl[b2] = o2; Bl[b3] = o3;
  }
  __syncthreads();

  if(!OUT3){
    float* Bg = B + (size_t)blockIdx.x*BSZ;
    for(int j = tid*4; j < BSZ; j += 512)
      *(float4*)&Bg[j] = *(const float4*)&Bl[j];
  } else {
    float s0=0.f, s1=0.f, s2=0.f;
    for(int j = tid; j < BSZ; j += 128){
      float v = Bl[j];
      s0 = fmaf(v, W3[j*3+0], s0);
      s1 = fmaf(v, W3[j*3+1], s1);
      s2 = fmaf(v, W3[j*3+2], s2);
    }
    float* r0 = red; float* r1 = red+128; float* r2 = red+256;
    r0[tid]=s0; r1[tid]=s1; r2[tid]=s2;
    __syncthreads();
    for(int st = 64; st > 0; st >>= 1){
      if(tid < st){ r0[tid]+=r0[tid+st]; r1[tid]+=r1[tid+st]; r2[tid]+=r2[tid+st]; }
      __syncthreads();
    }
    if(tid == 0 && node < NREAL){
      out[node*3+0] += r0[0]*(1.f/128.f);
      out[node*3+1] += r1[0]*(1.f/128.f);
      out[node*3+2] += r2[0]*(1.f/128.f);
    }
  }
}

// ------- scatter CIN=96: float2 channel pairs (48 lanes), z-parity waves, barrier-free ----
template<int RELU>
__global__ __launch_bounds__(128) void k_scat96(
    const float* __restrict__ feat, const float4* __restrict__ gw,
    const int4* __restrict__ gmz, const int* __restrict__ row_start,
    float* __restrict__ B, int node_base)
{
  constexpr int CIN = 96, BSZ = KK*CIN, NP = 48;
  __shared__ __align__(16) float Bl[BSZ];
  const int tid  = threadIdx.x;
  const int node = node_base + blockIdx.x;

  for(int j = tid*4; j < BSZ; j += 512)
    *(float4*)&Bl[j] = make_float4(0.f,0.f,0.f,0.f);

  const int e0 = row_start[node], e1 = row_start[node+1];
  const int wv   = tid >> 6;
  const int lane = tid & 63;
  const bool act = (lane < NP);
  float2* Bp2 = (float2*)Bl;
  __syncthreads();

  if(act){
    #pragma unroll 2
    for(int e = e0; e < e1; ++e){
      const float4 q  = gw[e];
      const int4   md = gmz[e];
      const float zA = __int_as_float(md.x);
      const float z  = wv ? (1.f - zA) : zA;
      const int   cp = wv ? md.z : md.y;
      float2 v2 = ((const float2*)(feat + (size_t)md.w*CIN))[lane];
      if(RELU){ v2.x = fmaxf(v2.x,0.f); v2.y = fmaxf(v2.y,0.f); }
      v2.x *= z; v2.y *= z;
      const int b0 = ( cp        & 255)*NP + lane;
      const int b1 = ((cp >> 8)  & 255)*NP + lane;
      const int b2 = ((cp >> 16) & 255)*NP + lane;
      const int b3 = (((unsigned)cp) >> 24)*NP + lane;
      float2 o0 = Bp2[b0], o1 = Bp2[b1], o2 = Bp2[b2], o3 = Bp2[b3];
      o0.x = fmaf(q.x, v2.x, o0.x); o0.y = fmaf(q.x, v2.y, o0.y);
      o1.x = fmaf(q.y, v2.x, o1.x); o1.y = fmaf(q.y, v2.y, o1.y);
      o2.x = fmaf(q.z, v2.x, o2.x); o2.y = fmaf(q.z, v2.y, o2.y);
      o3.x = fmaf(q.w, v2.x, o3.x); o3.y = fmaf(q.w, v2.y, o3.y);
      Bp2[b0] = o0; Bp2[b1] = o1; Bp2[b2] = o2; Bp2[b3] = o3;
    }
  }
  __syncthreads();

  float* Bg = B + (size_t)blockIdx.x*BSZ;
  for(int j = tid*4; j < BSZ; j += 512)
    *(float4*)&Bg[j] = *(const float4*)&Bl[j];
}

// ------- scatter CIN=13: 4 edge-slots/wave (slot-private copies), z-parity waves ----------
__global__ __launch_bounds__(128) void k_scat13(
    const float* __restrict__ feat, const float4* __restrict__ gw,
    const int4* __restrict__ gmz, const int* __restrict__ row_start,
    float* __restrict__ B, int node_base)
{
  constexpr int CIN = 13, BSZ = KK*CIN, ESW = 4, CSTRIDE = BSZ + 8;
  __shared__ __align__(16) float Bl[ESW*CSTRIDE];
  const int tid  = threadIdx.x;
  const int node = node_base + blockIdx.x;

  for(int j = tid; j < ESW*CSTRIDE; j += 128) Bl[j] = 0.f;

  const int e0 = row_start[node], e1 = row_start[node+1];
  const int wv   = tid >> 6;
  const int lane = tid & 63;
  const int slot = lane >> 4;
  const int c    = lane & 15;
  const bool act = (c < CIN);
  float* Bp = Bl + slot*CSTRIDE;
  __syncthreads();

  if(act){
    for(int e = e0 + slot; e < e1; e += ESW){
      const float4 q  = gw[e];
      const int4   md = gmz[e];
      const float zA = __int_as_float(md.x);
      const float z  = wv ? (1.f - zA) : zA;
      const int   cp = wv ? md.z : md.y;
      float v = feat[(size_t)md.w*CIN + c] * z;
      const int b0 = ( cp        & 255)*CIN + c;
      const int b1 = ((cp >> 8)  & 255)*CIN + c;
      const int b2 = ((cp >> 16) & 255)*CIN + c;
      const int b3 = (((unsigned)cp) >> 24)*CIN + c;
      float o0 = Bp[b0], o1 = Bp[b1], o2 = Bp[b2], o3 = Bp[b3];
      o0 = fmaf(q.x, v, o0); o1 = fmaf(q.y, v, o1);
      o2 = fmaf(q.z, v, o2); o3 = fmaf(q.w, v, o3);
      Bp[b0] = o0; Bp[b1] = o1; Bp[b2] = o2; Bp[b3] = o3;
    }
  }
  __syncthreads();

  float* Bg = B + (size_t)blockIdx.x*BSZ;
  for(int j = tid*4; j < BSZ; j += 512){
    float4 a = *(const float4*)&Bl[j];
    #pragma unroll
    for(int k = 1; k < ESW; ++k){
      const float4 t = *(const float4*)&Bl[k*CSTRIDE + j];
      a.x += t.x; a.y += t.y; a.z += t.z; a.w += t.w;
    }
    *(float4*)&Bg[j] = a;
  }
}

// ---- GEMM, no atomics: P[s][node][64] = sum_{k in split s} A[row,k]*W[k,o]
__global__ __launch_bounds__(256) void k_gemm2(
    const float* __restrict__ A, const float* __restrict__ W,
    float* __restrict__ P, int M, int Kd, int node_base, int ktiles_per)
{
  __shared__ __align__(16) float As[16][68];   // [k][row]
  __shared__ __align__(16) float Ws[16][64];   // [k][col]
  const int tid = threadIdx.x;
  const int mbase = blockIdx.x * 64;
  const int s = blockIdx.y;
  const int kt0 = s * ktiles_per * 16;
  const int kt1 = min(Kd, kt0 + ktiles_per*16);
  const int ty = tid >> 4, tx = tid & 15;
  const int arow = tid >> 2, ako = (tid & 3) * 4;
  const int wk = tid >> 4,  wc = (tid & 15) * 4;

  float acc[4][4];
  #pragma unroll
  for(int i=0;i<4;++i)
    #pragma unroll
    for(int j=0;j<4;++j) acc[i][j] = 0.f;

  for(int kt = kt0; kt < kt1; kt += 16){
    float4 av = make_float4(0.f,0.f,0.f,0.f);
    const int grow = mbase + arow;
    if(grow < M) av = *(const float4*)(A + (size_t)grow*Kd + kt + ako);
    const float4 wv = *(const float4*)(W + (size_t)(kt + wk)*64 + wc);
    As[ako+0][arow]=av.x; As[ako+1][arow]=av.y; As[ako+2][arow]=av.z; As[ako+3][arow]=av.w;
    *(float4*)&Ws[wk][wc] = wv;
    __syncthreads();
    #pragma unroll
    for(int kk = 0; kk < 16; ++kk){
      const float4 a = *(const float4*)&As[kk][ty*4];
      const float4 b = *(const float4*)&Ws[kk][tx*4];
      const float aa[4] = {a.x,a.y,a.z,a.w};
      const float bb[4] = {b.x,b.y,b.z,b.w};
      #pragma unroll
      for(int i=0;i<4;++i)
        #pragma unroll
        for(int j=0;j<4;++j) acc[i][j] = fmaf(aa[i], bb[j], acc[i][j]);
    }
    __syncthreads();
  }

  #pragma unroll
  for(int i=0;i<4;++i){
    const int row = mbase + ty*4 + i;
    if(row < M)
      *(float4*)(P + ((size_t)s*NPTS + node_base + row)*64 + tx*4) = *(float4*)&acc[i][0];
  }
}

// ---- combine partials: x[node*ldout+colofs+o] += sum_s P[s][node][o]
template<int S>
__global__ void k_combine(const float* __restrict__ P, float* __restrict__ x,
                          int ldout, int colofs)
{
  int idx = blockIdx.x*blockDim.x + threadIdx.x;
  if(idx >= NPTS*16) return;
  int node = idx >> 4, c4 = (idx & 15) * 4;
  float4 s = *(const float4*)(P + (size_t)node*64 + c4);
  #pragma unroll
  for(int k=1;k<S;++k){
    float4 t = *(const float4*)(P + ((size_t)k*NPTS + node)*64 + c4);
    s.x+=t.x; s.y+=t.y; s.z+=t.z; s.w+=t.w;
  }
  float* xp = x + (size_t)node*ldout + colofs + c4;
  float4 o = *(float4*)xp;
  o.x+=s.x; o.y+=s.y; o.z+=s.z; o.w+=s.w;
  *(float4*)xp = o;
}

// ---------------- dense paths ----------------
__global__ void k_dense0(const float* __restrict__ f, const float* __restrict__ dW,
                         const float* __restrict__ db, const float* __restrict__ cb0,
                         float* __restrict__ out)
{
  int idx = blockIdx.x*blockDim.x + threadIdx.x;
  if(idx >= NPTS*96) return;
  int i = idx/96, c = idx - i*96;
  if(c < 64){ out[idx] = cb0[c]; return; }
  int o = c - 64;
  float s = db[o];
  const float* row = f + (size_t)i*13;
  #pragma unroll
  for(int j=0;j<13;++j) s = fmaf(row[j], dW[j*32+o], s);
  out[idx] = s;
}

__global__ void k_dense(const float* __restrict__ in, int cin,
                        const float* __restrict__ dW, const float* __restrict__ db,
                        const float* __restrict__ cb, const float* __restrict__ resid,
                        float* __restrict__ out)
{
  int idx = blockIdx.x*blockDim.x + threadIdx.x;
  if(idx >= NPTS*64) return;
  int i = idx >> 6, o = idx & 63;
  float s = db[o] + cb[o];
  if(resid) s += resid[idx];
  const float* row = in + (size_t)i*cin;
  for(int c=0;c<cin;++c) s = fmaf(fmaxf(row[c],0.f), dW[c*64+o], s);
  out[idx] = s;
}

__global__ void k_dense3(const float* __restrict__ x2, const float* __restrict__ dW,
                         const float* __restrict__ db, const float* __restrict__ cb,
                         float* __restrict__ out)
{
  int idx = blockIdx.x*blockDim.x + threadIdx.x;
  if(idx >= NREAL*3) return;
  int i = idx/3, o = idx - i*3;
  float s = db[o] + cb[o];
  const float* row = x2 + (size_t)i*64;
  for(int c=0;c<64;++c) s = fmaf(fmaxf(row[c],0.f), dW[c*3+o], s);
  out[idx] = s * (1.f/128.f);
}

// ---------------- host ----------------
static inline size_t alup(size_t x){ return (x + 255) & ~(size_t)255; }

static inline int calc_rows(size_t bcap, int cin, int want){
  size_t perrow = (size_t)KK * cin * 4;
  size_t r = (perrow > 0) ? bcap / perrow : 0;
  if(r >= (size_t)want) return want;
  r = (r / 128) * 128;
  if(r < 128) r = 128;
  return (int)r;
}

extern "C" void kernel_launch(void* const* d_in, const int* in_sizes, int n_in,
                              void* d_out, int out_size, void* d_ws, size_t ws_size,
                              hipStream_t stream)
{
  const float* pos   = (const float*)d_in[0];
  const float* feats = (const float*)d_in[1];
  const int*   esrc  = (const int*)d_in[2];
  const int*   edst  = (const int*)d_in[3];
  const float* c0w = (const float*)d_in[4];
  const float* c0b = (const float*)d_in[5];
  const float* d0w = (const float*)d_in[6];
  const float* d0b = (const float*)d_in[7];
  const float* c1w = (const float*)d_in[8];
  const float* c1b = (const float*)d_in[9];
  const float* d1w = (const float*)d_in[10];
  const float* d1b = (const float*)d_in[11];
  const float* c2w = (const float*)d_in[12];
  const float* c2b = (const float*)d_in[13];
  const float* d2w = (const float*)d_in[14];
  const float* d2b = (const float*)d_in[15];
  const float* c3w = (const float*)d_in[16];
  const float* c3b = (const float*)d_in[17];
  const float* d3w = (const float*)d_in[18];
  const float* d3b = (const float*)d_in[19];
  float* out = (float*)d_out;

  char* w = (char*)d_ws;
  size_t off = 0;
  float* f  = (float*)(w+off); off += alup((size_t)NPTS*13*4);
  float* x0 = (float*)(w+off); off += alup((size_t)NPTS*96*4);
  float* x1 = (float*)(w+off); off += alup((size_t)NPTS*64*4);
  float* x2 = (float*)(w+off); off += alup((size_t)NPTS*64*4);
  int* row_start = (int*)(w+off); off += alup((size_t)(NPTS+1)*4);
  int* ereal = (int*)(w+off);     off += alup(16);
  float4* gw = (float4*)(w+off);  off += alup((size_t)EPAD*16);    // per-edge xy weights
  int4*  gmz = (int4*)(w+off);    off += alup((size_t)EPAD*16);    // per-edge zA+cells+dst
  float* P  = (float*)(w+off); off += alup((size_t)16*NPTS*64*4);  // split-K partials (S<=16)
  float* B = (float*)(w+off);
  size_t bcap = (ws_size > off) ? (ws_size - off) : 0;

  k_find_ereal<<<1,1,0,stream>>>(edst, ereal);
  k_csr<<<(NPTS+1+255)/256,256,0,stream>>>(esrc, ereal, row_start);
  k_build_f<<<(NPTS*13+255)/256,256,0,stream>>>(feats, f);
  k_geom<<<(EPAD+255)/256,256,0,stream>>>(pos, esrc, edst, gw, gmz);

  // ---- layer 0: x0[:,0:64] = cconv0(f)+c0b ; x0[:,64:96] = f@d0w+d0b  (chunk 8192)
  k_dense0<<<(NPTS*96+255)/256,256,0,stream>>>(f, d0w, d0b, c0b, x0);
  {
    int rows = calc_rows(bcap, 13, 8192);
    for(int base = 0; base < NPTS; base += rows){
      int m = (NPTS - base < rows) ? (NPTS - base) : rows;
      k_scat13<<<m,128,0,stream>>>(f, gw, gmz, row_start, B, base);
      k_gemm2<<<dim3((m+63)/64, 8),256,0,stream>>>(B, c0w, P, m, 832, base, 7);
    }
    k_combine<8><<<(NPTS*16+255)/256,256,0,stream>>>(P, x0, 96, 0);
  }

  // ---- layer 1: x1 = cconv1(relu(x0)) + relu(x0)@d1w + d1b + c1b   (chunk 2048)
  k_dense<<<(NPTS*64+255)/256,256,0,stream>>>(x0, 96, d1w, d1b, c1b, nullptr, x1);
  {
    int rows = calc_rows(bcap, 96, 2048);
    for(int base = 0; base < NPTS; base += rows){
      int m = (NPTS - base < rows) ? (NPTS - base) : rows;
      k_scat96<1><<<m,128,0,stream>>>(x0, gw, gmz, row_start, B, base);
      k_gemm2<<<dim3((m+63)/64, 16),256,0,stream>>>(B, c1w, P, m, 6144, base, 24);
    }
    k_combine<16><<<(NPTS*16+255)/256,256,0,stream>>>(P, x1, 64, 0);
  }

  // ---- layer 2: x2 = cconv2(relu(x1)) + relu(x1)@d2w + d2b + c2b + x1  (chunk 3072)
  k_dense<<<(NPTS*64+255)/256,256,0,stream>>>(x1, 64, d2w, d2b, c2b, x1, x2);
  {
    int rows = calc_rows(bcap, 64, 3072);
    for(int base = 0; base < NPTS; base += rows){
      int m = (NPTS - base < rows) ? (NPTS - base) : rows;
      k_scat64<1,0><<<m,128,0,stream>>>(x1, gw, gmz, row_start, B, base, nullptr, nullptr);
      k_gemm2<<<dim3((m+63)/64, 16),256,0,stream>>>(B, c2w, P, m, 4096, base, 16);
    }
    k_combine<16><<<(NPTS*16+255)/256,256,0,stream>>>(P, x2, 64, 0);
  }

  // ---- layer 3 (fused): out = dense3 part, then scatter adds conv3 GEMV directly
  k_dense3<<<(NREAL*3+255)/256,256,0,stream>>>(x2, d3w, d3b, c3b, out);
  k_scat64<1,1><<<NPTS,128,0,stream>>>(x2, gw, gmz, row_start, nullptr, 0, c3w, out);
}

// Round 13
// 1445.384 us; speedup vs baseline: 1.1548x; 1.0383x over previous
//
#include <hip/hip_runtime.h>
#include <math.h>

#define NPTS   20001
#define NREAL  20000
#define EPAD   1200000
#define KK     64
#define RADF   0.1125f

__device__ __forceinline__ float sgnf(float v){ return v>0.f ? 1.f : (v<0.f ? -1.f : 0.f); }

// ---------------- CSR build (edge_src is sorted; pad edges have dst==NREAL) ----------------
__global__ void k_find_ereal(const int* __restrict__ dst, int* __restrict__ ereal){
  int lo=0, hi=EPAD;
  while(lo<hi){ int mid=(lo+hi)>>1; if(dst[mid]==NREAL) hi=mid; else lo=mid+1; }
  *ereal = lo;
}

__global__ void k_csr(const int* __restrict__ src, const int* __restrict__ erealp,
                      int* __restrict__ row_start){
  int i = blockIdx.x*blockDim.x + threadIdx.x;
  if(i > NPTS) return;
  int E = *erealp;
  int lo=0, hi=E;
  while(lo<hi){ int mid=(lo+hi)>>1; if(src[mid] < i) lo=mid+1; else hi=mid; }
  row_start[i] = lo;
}

__global__ void k_build_f(const float* __restrict__ feats, float* __restrict__ f){
  int idx = blockIdx.x*blockDim.x + threadIdx.x;
  if(idx >= NPTS*13) return;
  int i = idx/13, c = idx - i*13;
  f[idx] = (c==0) ? 1.f : feats[i*12 + (c-1)];
}

// ---------------- per-edge geometry (exact port of ball_to_cube + window) ----------------
__device__ __forceinline__ void edge_geom(float ox, float oy, float oz,
                                          float& win, float& t0, float& t1, float& t2, int& f0p){
  const float eps = 1e-9f;
  float sq = ox*ox + oy*oy + oz*oz;
  float u = 1.f - sq;
  win = fminf(fmaxf(u*u*u, 0.f), 1.f);
  float norm = sqrtf(sq + eps);
  float rxy2 = ox*ox + oy*oy;
  bool polar = (1.25f*oz*oz > rxy2);
  float s_p = sqrtf(3.f*norm/(norm + fabsf(oz) + eps));
  float s_n = norm / sqrtf(rxy2 + eps);
  float s = polar ? s_p : s_n;
  float xc = ox*s, yc = oy*s;
  float zc = polar ? sgnf(oz)*norm : 1.5f*oz;
  if(sq < 1e-12f){ xc = 0.f; yc = 0.f; zc = 0.f; }
  float r = sqrtf(xc*xc + yc*yc + eps);
  bool c1 = fabsf(xc) >= fabsf(yc);
  float xs = (fabsf(xc) < eps) ? eps : xc;
  float ys = (fabsf(yc) < eps) ? eps : yc;
  const float fop = 1.2732395447351628f; // float32(4/pi)
  float a = c1 ? sgnf(xc)*r : sgnf(yc)*r*fop*atanf(xc/ys);
  float b = c1 ? sgnf(xc)*r*fop*atanf(yc/xs) : sgnf(yc)*r;
  if(xc*xc + yc*yc < 1e-12f){ a = 0.f; b = 0.f; }
  float g0 = fminf(fmaxf((a *0.5f+0.5f)*3.f, 0.f), 3.f);
  float g1 = fminf(fmaxf((b *0.5f+0.5f)*3.f, 0.f), 3.f);
  float g2 = fminf(fmaxf((zc*0.5f+0.5f)*3.f, 0.f), 3.f);
  float f00 = floorf(g0), f01 = floorf(g1), f02 = floorf(g2);
  t0 = g0 - f00; t1 = g1 - f01; t2 = g2 - f02;
  f0p = (int)f00 | ((int)f01 << 2) | ((int)f02 << 4);
}

// ---- k_geom: per-edge staged data, computed ONCE (shared by all 4 scatter layers).
// gw[e]  = win-premultiplied xy-quad weights {q00,q01,q10,q11}
// gmz[e] = {bits(zA), cells0, cells1, dst}; zB = 1-zA (wz0+wz1==1 exactly).
// min(i+1,3) -> (i+1)&3 is exact (clamped corner has t==0 weight): all 8 cells distinct ->
// batched read/fma/write in the scatters is race-free; parity-p cells owned by wave p.
__global__ __launch_bounds__(256) void k_geom(const float* __restrict__ pos,
    const int* __restrict__ esrc, const int* __restrict__ edst,
    float4* __restrict__ gw, int4* __restrict__ gmz)
{
  int e = blockIdx.x*blockDim.x + threadIdx.x;
  if(e >= EPAD) return;
  const int sn = esrc[e], d = edst[e];
  const float ox = (pos[d*3+0]-pos[sn*3+0])/RADF;
  const float oy = (pos[d*3+1]-pos[sn*3+1])/RADF;
  const float oz = (pos[d*3+2]-pos[sn*3+2])/RADF;
  float win, t0, t1, t2; int f0p;
  edge_geom(ox, oy, oz, win, t0, t1, t2, f0p);
  const int i0 = f0p & 3, i1 = (f0p>>2) & 3, i2 = f0p >> 4;
  const int X0 = i0 << 4, X1 = ((i0+1)&3) << 4;
  const int Y0 = i1 << 2, Y1 = ((i1+1)&3) << 2;
  const int Z0 = i2, Z1 = (i2+1) & 3;
  const float wx0 = win*(1.f-t0), wx1 = win*t0;
  const float wy0 = 1.f-t1, wy1 = t1;
  const float wz0 = 1.f-t2, wz1 = t2;
  gw[e] = make_float4(wx0*wy0, wx0*wy1, wx1*wy0, wx1*wy1);
  const int p0 = Z0 & 1;
  const float zA = p0 ? wz1 : wz0;                  // weight for parity-0 (even z) cell
  const int   cA = p0 ? Z1 : Z0;                    // even-z cell
  const int   cB = p0 ? Z0 : Z1;                    // odd-z cell
  const int cells0 = (X0|Y0|cA) | ((X0|Y1|cA)<<8) | ((X1|Y0|cA)<<16) | ((X1|Y1|cA)<<24);
  const int cells1 = (X0|Y0|cB) | ((X0|Y1|cB)<<8) | ((X1|Y0|cB)<<16) | ((X1|Y1|cB)<<24);
  gmz[e] = make_int4(__float_as_int(zA), cells0, cells1, d);
}

// ------- scatter CIN=64: 2 waves (z-parity), lane = channel, barrier-free, SW-pipelined.
// Prefetch depth 2 on gw/gmz, depth 1 on the feat gather -> global latency off the RMW chain.
// OUT3=1: fused cout=3 GEMV epilogue (layer 3).
template<int RELU, int OUT3>
__global__ __launch_bounds__(128) void k_scat64(
    const float* __restrict__ feat, const float4* __restrict__ gw,
    const int4* __restrict__ gmz, const int* __restrict__ row_start,
    float* __restrict__ B, int node_base,
    const float* __restrict__ W3, float* __restrict__ out)
{
  constexpr int BSZ = 64*64;
  __shared__ __align__(16) float Bl[BSZ];
  __shared__ float red[OUT3 ? 384 : 4];
  const int tid  = threadIdx.x;
  const int node = node_base + blockIdx.x;

  for(int j = tid*4; j < BSZ; j += 512)
    *(float4*)&Bl[j] = make_float4(0.f,0.f,0.f,0.f);

  const int e0 = row_start[node], e1 = row_start[node+1];
  const int wv = tid >> 6;          // z-parity owned by this wave
  const int c  = tid & 63;          // owned channel
  __syncthreads();

  if(e0 < e1){
    const int last = e1 - 1;
    int e1c = (e0+1 <= last) ? e0+1 : last;
    float4 q0 = gw[e0], q1 = gw[e1c];
    int4  md0 = gmz[e0], md1 = gmz[e1c];
    float  v0 = feat[(size_t)md0.w*64 + c];
    for(int e = e0; e < e1; ++e){
      const int e2 = (e+2 <= last) ? e+2 : last;
      const float4 q2 = gw[e2];
      const int4  md2 = gmz[e2];
      const float  v1 = feat[(size_t)md1.w*64 + c];
      // process (q0, md0, v0)
      const float zA = __int_as_float(md0.x);
      const float z  = wv ? (1.f - zA) : zA;
      const int   cp = wv ? md0.z : md0.y;
      float v = v0;
      if(RELU) v = fmaxf(v, 0.f);
      v *= z;
      const int b0 = (( cp        & 255) << 6) + c;
      const int b1 = (((cp >> 8)  & 255) << 6) + c;
      const int b2 = (((cp >> 16) & 255) << 6) + c;
      const int b3 = ((((unsigned)cp) >> 24) << 6) + c;
      float o0 = Bl[b0], o1 = Bl[b1], o2 = Bl[b2], o3 = Bl[b3];
      o0 = fmaf(q0.x, v, o0); o1 = fmaf(q0.y, v, o1);
      o2 = fmaf(q0.z, v, o2); o3 = fmaf(q0.w, v, o3);
      Bl[b0] = o0; Bl[b1] = o1; Bl[b2] = o2; Bl[b3] = o3;
      q0 = q1; md0 = md1; v0 = v1;
      q1 = q2; md1 = md2;
    }
  }
  __syncthreads();

  if(!OUT3){
    float* Bg = B + (size_t)blockIdx.x*BSZ;
    for(int j = tid*4; j < BSZ; j += 512)
      *(float4*)&Bg[j] = *(const float4*)&Bl[j];
  } else {
    float s0=0.f, s1=0.f, s2=0.f;
    for(int j = tid; j < BSZ; j += 128){
      float v = Bl[j];
      s0 = fmaf(v, W3[j*3+0], s0);
      s1 = fmaf(v, W3[j*3+1], s1);
      s2 = fmaf(v, W3[j*3+2], s2);
    }
    float* r0 = red; float* r1 = red+128; float* r2 = red+256;
    r0[tid]=s0; r1[tid]=s1; r2[tid]=s2;
    __syncthreads();
    for(int st = 64; st > 0; st >>= 1){
      if(tid < st){ r0[tid]+=r0[tid+st]; r1[tid]+=r1[tid+st]; r2[tid]+=r2[tid+st]; }
      __syncthreads();
    }
    if(tid == 0 && node < NREAL){
      out[node*3+0] += r0[0]*(1.f/128.f);
      out[node*3+1] += r1[0]*(1.f/128.f);
      out[node*3+2] += r2[0]*(1.f/128.f);
    }
  }
}

// ------- scatter CIN=96: float2 channel pairs (48 lanes), z-parity waves, SW-pipelined ----
template<int RELU>
__global__ __launch_bounds__(128) void k_scat96(
    const float* __restrict__ feat, const float4* __restrict__ gw,
    const int4* __restrict__ gmz, const int* __restrict__ row_start,
    float* __restrict__ B, int node_base)
{
  constexpr int CIN = 96, BSZ = KK*CIN, NP = 48;
  __shared__ __align__(16) float Bl[BSZ];
  const int tid  = threadIdx.x;
  const int node = node_base + blockIdx.x;

  for(int j = tid*4; j < BSZ; j += 512)
    *(float4*)&Bl[j] = make_float4(0.f,0.f,0.f,0.f);

  const int e0 = row_start[node], e1 = row_start[node+1];
  const int wv   = tid >> 6;
  const int lane = tid & 63;
  const bool act = (lane < NP);
  float2* Bp2 = (float2*)Bl;
  __syncthreads();

  if(act && e0 < e1){
    const int last = e1 - 1;
    int e1c = (e0+1 <= last) ? e0+1 : last;
    float4 q0 = gw[e0], q1 = gw[e1c];
    int4  md0 = gmz[e0], md1 = gmz[e1c];
    float2 v0 = ((const float2*)(feat + (size_t)md0.w*CIN))[lane];
    for(int e = e0; e < e1; ++e){
      const int e2 = (e+2 <= last) ? e+2 : last;
      const float4 q2 = gw[e2];
      const int4  md2 = gmz[e2];
      const float2 v1 = ((const float2*)(feat + (size_t)md1.w*CIN))[lane];
      const float zA = __int_as_float(md0.x);
      const float z  = wv ? (1.f - zA) : zA;
      const int   cp = wv ? md0.z : md0.y;
      float2 v2 = v0;
      if(RELU){ v2.x = fmaxf(v2.x,0.f); v2.y = fmaxf(v2.y,0.f); }
      v2.x *= z; v2.y *= z;
      const int b0 = ( cp        & 255)*NP + lane;
      const int b1 = ((cp >> 8)  & 255)*NP + lane;
      const int b2 = ((cp >> 16) & 255)*NP + lane;
      const int b3 = (((unsigned)cp) >> 24)*NP + lane;
      float2 o0 = Bp2[b0], o1 = Bp2[b1], o2 = Bp2[b2], o3 = Bp2[b3];
      o0.x = fmaf(q0.x, v2.x, o0.x); o0.y = fmaf(q0.x, v2.y, o0.y);
      o1.x = fmaf(q0.y, v2.x, o1.x); o1.y = fmaf(q0.y, v2.y, o1.y);
      o2.x = fmaf(q0.z, v2.x, o2.x); o2.y = fmaf(q0.z, v2.y, o2.y);
      o3.x = fmaf(q0.w, v2.x, o3.x); o3.y = fmaf(q0.w, v2.y, o3.y);
      Bp2[b0] = o0; Bp2[b1] = o1; Bp2[b2] = o2; Bp2[b3] = o3;
      q0 = q1; md0 = md1; v0 = v1;
      q1 = q2; md1 = md2;
    }
  }
  __syncthreads();

  float* Bg = B + (size_t)blockIdx.x*BSZ;
  for(int j = tid*4; j < BSZ; j += 512)
    *(float4*)&Bg[j] = *(const float4*)&Bl[j];
}

// ------- scatter CIN=13: 4 edge-slots/wave (slot-private copies), z-parity, pipelined -----
__global__ __launch_bounds__(128) void k_scat13(
    const float* __restrict__ feat, const float4* __restrict__ gw,
    const int4* __restrict__ gmz, const int* __restrict__ row_start,
    float* __restrict__ B, int node_base)
{
  constexpr int CIN = 13, BSZ = KK*CIN, ESW = 4, CSTRIDE = BSZ + 8;
  __shared__ __align__(16) float Bl[ESW*CSTRIDE];
  const int tid  = threadIdx.x;
  const int node = node_base + blockIdx.x;

  for(int j = tid; j < ESW*CSTRIDE; j += 128) Bl[j] = 0.f;

  const int e0 = row_start[node], e1 = row_start[node+1];
  const int wv   = tid >> 6;
  const int lane = tid & 63;
  const int slot = lane >> 4;
  const int c    = lane & 15;
  const bool act = (c < CIN);
  float* Bp = Bl + slot*CSTRIDE;
  __syncthreads();

  if(act && e0 + slot < e1){
    const int last = e1 - 1;
    int e = e0 + slot;
    int enx = (e+ESW <= last) ? e+ESW : e;
    float4 q0 = gw[e], q1 = gw[enx];
    int4  md0 = gmz[e], md1 = gmz[enx];
    float  v0 = feat[(size_t)md0.w*CIN + c];
    for(; e < e1; e += ESW){
      const int e2 = (e+2*ESW <= last) ? e+2*ESW : enx;
      const float4 q2 = gw[e2];
      const int4  md2 = gmz[e2];
      const float  v1 = feat[(size_t)md1.w*CIN + c];
      const float zA = __int_as_float(md0.x);
      const float z  = wv ? (1.f - zA) : zA;
      const int   cp = wv ? md0.z : md0.y;
      const float v = v0 * z;
      const int b0 = ( cp        & 255)*CIN + c;
      const int b1 = ((cp >> 8)  & 255)*CIN + c;
      const int b2 = ((cp >> 16) & 255)*CIN + c;
      const int b3 = (((unsigned)cp) >> 24)*CIN + c;
      float o0 = Bp[b0], o1 = Bp[b1], o2 = Bp[b2], o3 = Bp[b3];
      o0 = fmaf(q0.x, v, o0); o1 = fmaf(q0.y, v, o1);
      o2 = fmaf(q0.z, v, o2); o3 = fmaf(q0.w, v, o3);
      Bp[b0] = o0; Bp[b1] = o1; Bp[b2] = o2; Bp[b3] = o3;
      q0 = q1; md0 = md1; v0 = v1;
      q1 = q2; md1 = md2;
      enx = e2;
    }
  }
  __syncthreads();

  float* Bg = B + (size_t)blockIdx.x*BSZ;
  for(int j = tid*4; j < BSZ; j += 512){
    float4 a = *(const float4*)&Bl[j];
    #pragma unroll
    for(int k = 1; k < ESW; ++k){
      const float4 t = *(const float4*)&Bl[k*CSTRIDE + j];
      a.x += t.x; a.y += t.y; a.z += t.z; a.w += t.w;
    }
    *(float4*)&Bg[j] = a;
  }
}

// ---- GEMM, no atomics: P[s][node][64] = sum_{k in split s} A[row,k]*W[k,o]
__global__ __launch_bounds__(256) void k_gemm2(
    const float* __restrict__ A, const float* __restrict__ W,
    float* __restrict__ P, int M, int Kd, int node_base, int ktiles_per)
{
  __shared__ __align__(16) float As[16][68];   // [k][row]
  __shared__ __align__(16) float Ws[16][64];   // [k][col]
  const int tid = threadIdx.x;
  const int mbase = blockIdx.x * 64;
  const int s = blockIdx.y;
  const int kt0 = s * ktiles_per * 16;
  const int kt1 = min(Kd, kt0 + ktiles_per*16);
  const int ty = tid >> 4, tx = tid & 15;
  const int arow = tid >> 2, ako = (tid & 3) * 4;
  const int wk = tid >> 4,  wc = (tid & 15) * 4;

  float acc[4][4];
  #pragma unroll
  for(int i=0;i<4;++i)
    #pragma unroll
    for(int j=0;j<4;++j) acc[i][j] = 0.f;

  for(int kt = kt0; kt < kt1; kt += 16){
    float4 av = make_float4(0.f,0.f,0.f,0.f);
    const int grow = mbase + arow;
    if(grow < M) av = *(const float4*)(A + (size_t)grow*Kd + kt + ako);
    const float4 wv = *(const float4*)(W + (size_t)(kt + wk)*64 + wc);
    As[ako+0][arow]=av.x; As[ako+1][arow]=av.y; As[ako+2][arow]=av.z; As[ako+3][arow]=av.w;
    *(float4*)&Ws[wk][wc] = wv;
    __syncthreads();
    #pragma unroll
    for(int kk = 0; kk < 16; ++kk){
      const float4 a = *(const float4*)&As[kk][ty*4];
      const float4 b = *(const float4*)&Ws[kk][tx*4];
      const float aa[4] = {a.x,a.y,a.z,a.w};
      const float bb[4] = {b.x,b.y,b.z,b.w};
      #pragma unroll
      for(int i=0;i<4;++i)
        #pragma unroll
        for(int j=0;j<4;++j) acc[i][j] = fmaf(aa[i], bb[j], acc[i][j]);
    }
    __syncthreads();
  }

  #pragma unroll
  for(int i=0;i<4;++i){
    const int row = mbase + ty*4 + i;
    if(row < M)
      *(float4*)(P + ((size_t)s*NPTS + node_base + row)*64 + tx*4) = *(float4*)&acc[i][0];
  }
}

// ---- combine partials: x[node*ldout+colofs+o] += sum_s P[s][node][o]
template<int S>
__global__ void k_combine(const float* __restrict__ P, float* __restrict__ x,
                          int ldout, int colofs)
{
  int idx = blockIdx.x*blockDim.x + threadIdx.x;
  if(idx >= NPTS*16) return;
  int node = idx >> 4, c4 = (idx & 15) * 4;
  float4 s = *(const float4*)(P + (size_t)node*64 + c4);
  #pragma unroll
  for(int k=1;k<S;++k){
    float4 t = *(const float4*)(P + ((size_t)k*NPTS + node)*64 + c4);
    s.x+=t.x; s.y+=t.y; s.z+=t.z; s.w+=t.w;
  }
  float* xp = x + (size_t)node*ldout + colofs + c4;
  float4 o = *(float4*)xp;
  o.x+=s.x; o.y+=s.y; o.z+=s.z; o.w+=s.w;
  *(float4*)xp = o;
}

// ---------------- dense paths ----------------
__global__ void k_dense0(const float* __restrict__ f, const float* __restrict__ dW,
                         const float* __restrict__ db, const float* __restrict__ cb0,
                         float* __restrict__ out)
{
  int idx = blockIdx.x*blockDim.x + threadIdx.x;
  if(idx >= NPTS*96) return;
  int i = idx/96, c = idx - i*96;
  if(c < 64){ out[idx] = cb0[c]; return; }
  int o = c - 64;
  float s = db[o];
  const float* row = f + (size_t)i*13;
  #pragma unroll
  for(int j=0;j<13;++j) s = fmaf(row[j], dW[j*32+o], s);
  out[idx] = s;
}

__global__ void k_dense(const float* __restrict__ in, int cin,
                        const float* __restrict__ dW, const float* __restrict__ db,
                        const float* __restrict__ cb, const float* __restrict__ resid,
                        float* __restrict__ out)
{
  int idx = blockIdx.x*blockDim.x + threadIdx.x;
  if(idx >= NPTS*64) return;
  int i = idx >> 6, o = idx & 63;
  float s = db[o] + cb[o];
  if(resid) s += resid[idx];
  const float* row = in + (size_t)i*cin;
  for(int c=0;c<cin;++c) s = fmaf(fmaxf(row[c],0.f), dW[c*64+o], s);
  out[idx] = s;
}

__global__ void k_dense3(const float* __restrict__ x2, const float* __restrict__ dW,
                         const float* __restrict__ db, const float* __restrict__ cb,
                         float* __restrict__ out)
{
  int idx = blockIdx.x*blockDim.x + threadIdx.x;
  if(idx >= NREAL*3) return;
  int i = idx/3, o = idx - i*3;
  float s = db[o] + cb[o];
  const float* row = x2 + (size_t)i*64;
  for(int c=0;c<64;++c) s = fmaf(fmaxf(row[c],0.f), dW[c*3+o], s);
  out[idx] = s * (1.f/128.f);
}

// ---------------- host ----------------
static inline size_t alup(size_t x){ return (x + 255) & ~(size_t)255; }

static inline int calc_rows(size_t bcap, int cin, int want){
  size_t perrow = (size_t)KK * cin * 4;
  size_t r = (perrow > 0) ? bcap / perrow : 0;
  if(r >= (size_t)want) return want;
  r = (r / 128) * 128;
  if(r < 128) r = 128;
  return (int)r;
}

extern "C" void kernel_launch(void* const* d_in, const int* in_sizes, int n_in,
                              void* d_out, int out_size, void* d_ws, size_t ws_size,
                              hipStream_t stream)
{
  const float* pos   = (const float*)d_in[0];
  const float* feats = (const float*)d_in[1];
  const int*   esrc  = (const int*)d_in[2];
  const int*   edst  = (const int*)d_in[3];
  const float* c0w = (const float*)d_in[4];
  const float* c0b = (const float*)d_in[5];
  const float* d0w = (const float*)d_in[6];
  const float* d0b = (const float*)d_in[7];
  const float* c1w = (const float*)d_in[8];
  const float* c1b = (const float*)d_in[9];
  const float* d1w = (const float*)d_in[10];
  const float* d1b = (const float*)d_in[11];
  const float* c2w = (const float*)d_in[12];
  const float* c2b = (const float*)d_in[13];
  const float* d2w = (const float*)d_in[14];
  const float* d2b = (const float*)d_in[15];
  const float* c3w = (const float*)d_in[16];
  const float* c3b = (const float*)d_in[17];
  const float* d3w = (const float*)d_in[18];
  const float* d3b = (const float*)d_in[19];
  float* out = (float*)d_out;

  char* w = (char*)d_ws;
  size_t off = 0;
  float* f  = (float*)(w+off); off += alup((size_t)NPTS*13*4);
  float* x0 = (float*)(w+off); off += alup((size_t)NPTS*96*4);
  float* x1 = (float*)(w+off); off += alup((size_t)NPTS*64*4);
  float* x2 = (float*)(w+off); off += alup((size_t)NPTS*64*4);
  int* row_start = (int*)(w+off); off += alup((size_t)(NPTS+1)*4);
  int* ereal = (int*)(w+off);     off += alup(16);
  float4* gw = (float4*)(w+off);  off += alup((size_t)EPAD*16);    // per-edge xy weights
  int4*  gmz = (int4*)(w+off);    off += alup((size_t)EPAD*16);    // per-edge zA+cells+dst
  float* P  = (float*)(w+off); off += alup((size_t)8*NPTS*64*4);   // split-K partials (S<=8)
  float* B = (float*)(w+off);
  size_t bcap = (ws_size > off) ? (ws_size - off) : 0;

  k_find_ereal<<<1,1,0,stream>>>(edst, ereal);
  k_csr<<<(NPTS+1+255)/256,256,0,stream>>>(esrc, ereal, row_start);
  k_build_f<<<(NPTS*13+255)/256,256,0,stream>>>(feats, f);
  k_geom<<<(EPAD+255)/256,256,0,stream>>>(pos, esrc, edst, gw, gmz);

  // ---- layer 0: x0[:,0:64] = cconv0(f)+c0b ; x0[:,64:96] = f@d0w+d0b  (chunk 8192)
  k_dense0<<<(NPTS*96+255)/256,256,0,stream>>>(f, d0w, d0b, c0b, x0);
  {
    int rows = calc_rows(bcap, 13, 8192);
    for(int base = 0; base < NPTS; base += rows){
      int m = (NPTS - base < rows) ? (NPTS - base) : rows;
      k_scat13<<<m,128,0,stream>>>(f, gw, gmz, row_start, B, base);
      k_gemm2<<<dim3((m+63)/64, 8),256,0,stream>>>(B, c0w, P, m, 832, base, 7);
    }
    k_combine<8><<<(NPTS*16+255)/256,256,0,stream>>>(P, x0, 96, 0);
  }

  // ---- layer 1: x1 = cconv1(relu(x0)) + relu(x0)@d1w + d1b + c1b   (chunk 4096)
  k_dense<<<(NPTS*64+255)/256,256,0,stream>>>(x0, 96, d1w, d1b, c1b, nullptr, x1);
  {
    int rows = calc_rows(bcap, 96, 4096);
    for(int base = 0; base < NPTS; base += rows){
      int m = (NPTS - base < rows) ? (NPTS - base) : rows;
      k_scat96<1><<<m,128,0,stream>>>(x0, gw, gmz, row_start, B, base);
      k_gemm2<<<dim3((m+63)/64, 8),256,0,stream>>>(B, c1w, P, m, 6144, base, 48);
    }
    k_combine<8><<<(NPTS*16+255)/256,256,0,stream>>>(P, x1, 64, 0);
  }

  // ---- layer 2: x2 = cconv2(relu(x1)) + relu(x1)@d2w + d2b + c2b + x1  (chunk 4096)
  k_dense<<<(NPTS*64+255)/256,256,0,stream>>>(x1, 64, d2w, d2b, c2b, x1, x2);
  {
    int rows = calc_rows(bcap, 64, 4096);
    for(int base = 0; base < NPTS; base += rows){
      int m = (NPTS - base < rows) ? (NPTS - base) : rows;
      k_scat64<1,0><<<m,128,0,stream>>>(x1, gw, gmz, row_start, B, base, nullptr, nullptr);
      k_gemm2<<<dim3((m+63)/64, 8),256,0,stream>>>(B, c2w, P, m, 4096, base, 32);
    }
    k_combine<8><<<(NPTS*16+255)/256,256,0,stream>>>(P, x2, 64, 0);
  }

  // ---- layer 3 (fused): out = dense3 part, then scatter adds conv3 GEMV directly
  k_dense3<<<(NREAL*3+255)/256,256,0,stream>>>(x2, d3w, d3b, c3b, out);
  k_scat64<1,1><<<NPTS,128,0,stream>>>(x2, gw, gmz, row_start, nullptr, 0, c3w, out);
}

// Round 14
// 1386.096 us; speedup vs baseline: 1.2042x; 1.0428x over previous
//
#include <hip/hip_runtime.h>
#include <math.h>

#define NPTS   20001
#define NREAL  20000
#define EPAD   1200000
#define KK     64
#define RADF   0.1125f

__device__ __forceinline__ float sgnf(float v){ return v>0.f ? 1.f : (v<0.f ? -1.f : 0.f); }

// ---------------- CSR build (edge_src is sorted; pad edges have dst==NREAL) ----------------
__global__ void k_find_ereal(const int* __restrict__ dst, int* __restrict__ ereal){
  int lo=0, hi=EPAD;
  while(lo<hi){ int mid=(lo+hi)>>1; if(dst[mid]==NREAL) hi=mid; else lo=mid+1; }
  *ereal = lo;
}

__global__ void k_csr(const int* __restrict__ src, const int* __restrict__ erealp,
                      int* __restrict__ row_start){
  int i = blockIdx.x*blockDim.x + threadIdx.x;
  if(i > NPTS) return;
  int E = *erealp;
  int lo=0, hi=E;
  while(lo<hi){ int mid=(lo+hi)>>1; if(src[mid] < i) lo=mid+1; else hi=mid; }
  row_start[i] = lo;
}

__global__ void k_build_f(const float* __restrict__ feats, float* __restrict__ f){
  int idx = blockIdx.x*blockDim.x + threadIdx.x;
  if(idx >= NPTS*13) return;
  int i = idx/13, c = idx - i*13;
  f[idx] = (c==0) ? 1.f : feats[i*12 + (c-1)];
}

// ---------------- per-edge geometry (exact port of ball_to_cube + window) ----------------
__device__ __forceinline__ void edge_geom(float ox, float oy, float oz,
                                          float& win, float& t0, float& t1, float& t2, int& f0p){
  const float eps = 1e-9f;
  float sq = ox*ox + oy*oy + oz*oz;
  float u = 1.f - sq;
  win = fminf(fmaxf(u*u*u, 0.f), 1.f);
  float norm = sqrtf(sq + eps);
  float rxy2 = ox*ox + oy*oy;
  bool polar = (1.25f*oz*oz > rxy2);
  float s_p = sqrtf(3.f*norm/(norm + fabsf(oz) + eps));
  float s_n = norm / sqrtf(rxy2 + eps);
  float s = polar ? s_p : s_n;
  float xc = ox*s, yc = oy*s;
  float zc = polar ? sgnf(oz)*norm : 1.5f*oz;
  if(sq < 1e-12f){ xc = 0.f; yc = 0.f; zc = 0.f; }
  float r = sqrtf(xc*xc + yc*yc + eps);
  bool c1 = fabsf(xc) >= fabsf(yc);
  float xs = (fabsf(xc) < eps) ? eps : xc;
  float ys = (fabsf(yc) < eps) ? eps : yc;
  const float fop = 1.2732395447351628f; // float32(4/pi)
  float a = c1 ? sgnf(xc)*r : sgnf(yc)*r*fop*atanf(xc/ys);
  float b = c1 ? sgnf(xc)*r*fop*atanf(yc/xs) : sgnf(yc)*r;
  if(xc*xc + yc*yc < 1e-12f){ a = 0.f; b = 0.f; }
  float g0 = fminf(fmaxf((a *0.5f+0.5f)*3.f, 0.f), 3.f);
  float g1 = fminf(fmaxf((b *0.5f+0.5f)*3.f, 0.f), 3.f);
  float g2 = fminf(fmaxf((zc*0.5f+0.5f)*3.f, 0.f), 3.f);
  float f00 = floorf(g0), f01 = floorf(g1), f02 = floorf(g2);
  t0 = g0 - f00; t1 = g1 - f01; t2 = g2 - f02;
  f0p = (int)f00 | ((int)f01 << 2) | ((int)f02 << 4);
}

// ---- k_geom: per-edge staged data, computed ONCE (shared by all 4 scatter layers).
// gw[e]  = win-premultiplied xy-quad weights {q00,q01,q10,q11}
// gmz[e] = {bits(zA), cells0, cells1, dst}; zB = 1-zA (wz0+wz1==1 exactly).
// min(i+1,3) -> (i+1)&3 is exact (clamped corner has t==0 weight): all 8 cells distinct ->
// batched read/fma/write in the scatters is race-free; parity-p cells owned by wave p.
__global__ __launch_bounds__(256) void k_geom(const float* __restrict__ pos,
    const int* __restrict__ esrc, const int* __restrict__ edst,
    float4* __restrict__ gw, int4* __restrict__ gmz)
{
  int e = blockIdx.x*blockDim.x + threadIdx.x;
  if(e >= EPAD) return;
  const int sn = esrc[e], d = edst[e];
  const float ox = (pos[d*3+0]-pos[sn*3+0])/RADF;
  const float oy = (pos[d*3+1]-pos[sn*3+1])/RADF;
  const float oz = (pos[d*3+2]-pos[sn*3+2])/RADF;
  float win, t0, t1, t2; int f0p;
  edge_geom(ox, oy, oz, win, t0, t1, t2, f0p);
  const int i0 = f0p & 3, i1 = (f0p>>2) & 3, i2 = f0p >> 4;
  const int X0 = i0 << 4, X1 = ((i0+1)&3) << 4;
  const int Y0 = i1 << 2, Y1 = ((i1+1)&3) << 2;
  const int Z0 = i2, Z1 = (i2+1) & 3;
  const float wx0 = win*(1.f-t0), wx1 = win*t0;
  const float wy0 = 1.f-t1, wy1 = t1;
  const float wz0 = 1.f-t2, wz1 = t2;
  gw[e] = make_float4(wx0*wy0, wx0*wy1, wx1*wy0, wx1*wy1);
  const int p0 = Z0 & 1;
  const float zA = p0 ? wz1 : wz0;                  // weight for parity-0 (even z) cell
  const int   cA = p0 ? Z1 : Z0;                    // even-z cell
  const int   cB = p0 ? Z0 : Z1;                    // odd-z cell
  const int cells0 = (X0|Y0|cA) | ((X0|Y1|cA)<<8) | ((X1|Y0|cA)<<16) | ((X1|Y1|cA)<<24);
  const int cells1 = (X0|Y0|cB) | ((X0|Y1|cB)<<8) | ((X1|Y0|cB)<<16) | ((X1|Y1|cB)<<24);
  gmz[e] = make_int4(__float_as_int(zA), cells0, cells1, d);
}

// ------- scatter CIN=64: 2 waves (z-parity), lane = channel, barrier-free inner loop.
// Staged data read from global (broadcast address, L2/L3 resident). Single 16KB B copy.
// Plain loop (round-12 form): explicit SW pipelining measured SLOWER (192 vs 164 us) —
// wave-level TLP at 9 blocks/CU already hides the global latency; prefetch only added VALU.
// OUT3=1: fused cout=3 GEMV epilogue (layer 3).
template<int RELU, int OUT3>
__global__ __launch_bounds__(128) void k_scat64(
    const float* __restrict__ feat, const float4* __restrict__ gw,
    const int4* __restrict__ gmz, const int* __restrict__ row_start,
    float* __restrict__ B, int node_base,
    const float* __restrict__ W3, float* __restrict__ out)
{
  constexpr int BSZ = 64*64;
  __shared__ __align__(16) float Bl[BSZ];
  __shared__ float red[OUT3 ? 384 : 4];
  const int tid  = threadIdx.x;
  const int node = node_base + blockIdx.x;

  for(int j = tid*4; j < BSZ; j += 512)
    *(float4*)&Bl[j] = make_float4(0.f,0.f,0.f,0.f);

  const int e0 = row_start[node], e1 = row_start[node+1];
  const int wv = tid >> 6;          // z-parity owned by this wave
  const int c  = tid & 63;          // owned channel
  __syncthreads();

  #pragma unroll 2
  for(int e = e0; e < e1; ++e){
    const float4 q  = gw[e];
    const int4   md = gmz[e];
    const float zA = __int_as_float(md.x);
    const float z  = wv ? (1.f - zA) : zA;
    const int   cp = wv ? md.z : md.y;
    float v = feat[(size_t)md.w*64 + c];
    if(RELU) v = fmaxf(v, 0.f);
    v *= z;
    const int b0 = (( cp        & 255) << 6) + c;
    const int b1 = (((cp >> 8)  & 255) << 6) + c;
    const int b2 = (((cp >> 16) & 255) << 6) + c;
    const int b3 = ((((unsigned)cp) >> 24) << 6) + c;
    float o0 = Bl[b0], o1 = Bl[b1], o2 = Bl[b2], o3 = Bl[b3];
    o0 = fmaf(q.x, v, o0); o1 = fmaf(q.y, v, o1);
    o2 = fmaf(q.z, v, o2); o3 = fmaf(q.w, v, o3);
    Bl[b0] = o0; Bl[b1] = o1; Bl[b2] = o2; Bl[b3] = o3;
  }
  __syncthreads();

  if(!OUT3){
    float* Bg = B + (size_t)blockIdx.x*BSZ;
    for(int j = tid*4; j < BSZ; j += 512)
      *(float4*)&Bg[j] = *(const float4*)&Bl[j];
  } else {
    float s0=0.f, s1=0.f, s2=0.f;
    for(int j = tid; j < BSZ; j += 128){
      float v = Bl[j];
      s0 = fmaf(v, W3[j*3+0], s0);
      s1 = fmaf(v, W3[j*3+1], s1);
      s2 = fmaf(v, W3[j*3+2], s2);
    }
    float* r0 = red; float* r1 = red+128; float* r2 = red+256;
    r0[tid]=s0; r1[tid]=s1; r2[tid]=s2;
    __syncthreads();
    for(int st = 64; st > 0; st >>= 1){
      if(tid < st){ r0[tid]+=r0[tid+st]; r1[tid]+=r1[tid+st]; r2[tid]+=r2[tid+st]; }
      __syncthreads();
    }
    if(tid == 0 && node < NREAL){
      out[node*3+0] += r0[0]*(1.f/128.f);
      out[node*3+1] += r1[0]*(1.f/128.f);
      out[node*3+2] += r2[0]*(1.f/128.f);
    }
  }
}

// ------- scatter CIN=96: float2 channel pairs (48 lanes), z-parity waves, barrier-free ----
template<int RELU>
__global__ __launch_bounds__(128) void k_scat96(
    const float* __restrict__ feat, const float4* __restrict__ gw,
    const int4* __restrict__ gmz, const int* __restrict__ row_start,
    float* __restrict__ B, int node_base)
{
  constexpr int CIN = 96, BSZ = KK*CIN, NP = 48;
  __shared__ __align__(16) float Bl[BSZ];
  const int tid  = threadIdx.x;
  const int node = node_base + blockIdx.x;

  for(int j = tid*4; j < BSZ; j += 512)
    *(float4*)&Bl[j] = make_float4(0.f,0.f,0.f,0.f);

  const int e0 = row_start[node], e1 = row_start[node+1];
  const int wv   = tid >> 6;
  const int lane = tid & 63;
  const bool act = (lane < NP);
  float2* Bp2 = (float2*)Bl;
  __syncthreads();

  if(act){
    #pragma unroll 2
    for(int e = e0; e < e1; ++e){
      const float4 q  = gw[e];
      const int4   md = gmz[e];
      const float zA = __int_as_float(md.x);
      const float z  = wv ? (1.f - zA) : zA;
      const int   cp = wv ? md.z : md.y;
      float2 v2 = ((const float2*)(feat + (size_t)md.w*CIN))[lane];
      if(RELU){ v2.x = fmaxf(v2.x,0.f); v2.y = fmaxf(v2.y,0.f); }
      v2.x *= z; v2.y *= z;
      const int b0 = ( cp        & 255)*NP + lane;
      const int b1 = ((cp >> 8)  & 255)*NP + lane;
      const int b2 = ((cp >> 16) & 255)*NP + lane;
      const int b3 = (((unsigned)cp) >> 24)*NP + lane;
      float2 o0 = Bp2[b0], o1 = Bp2[b1], o2 = Bp2[b2], o3 = Bp2[b3];
      o0.x = fmaf(q.x, v2.x, o0.x); o0.y = fmaf(q.x, v2.y, o0.y);
      o1.x = fmaf(q.y, v2.x, o1.x); o1.y = fmaf(q.y, v2.y, o1.y);
      o2.x = fmaf(q.z, v2.x, o2.x); o2.y = fmaf(q.z, v2.y, o2.y);
      o3.x = fmaf(q.w, v2.x, o3.x); o3.y = fmaf(q.w, v2.y, o3.y);
      Bp2[b0] = o0; Bp2[b1] = o1; Bp2[b2] = o2; Bp2[b3] = o3;
    }
  }
  __syncthreads();

  float* Bg = B + (size_t)blockIdx.x*BSZ;
  for(int j = tid*4; j < BSZ; j += 512)
    *(float4*)&Bg[j] = *(const float4*)&Bl[j];
}

// ------- scatter CIN=13: 4 edge-slots/wave (slot-private copies), z-parity waves ----------
__global__ __launch_bounds__(128) void k_scat13(
    const float* __restrict__ feat, const float4* __restrict__ gw,
    const int4* __restrict__ gmz, const int* __restrict__ row_start,
    float* __restrict__ B, int node_base)
{
  constexpr int CIN = 13, BSZ = KK*CIN, ESW = 4, CSTRIDE = BSZ + 8;
  __shared__ __align__(16) float Bl[ESW*CSTRIDE];
  const int tid  = threadIdx.x;
  const int node = node_base + blockIdx.x;

  for(int j = tid; j < ESW*CSTRIDE; j += 128) Bl[j] = 0.f;

  const int e0 = row_start[node], e1 = row_start[node+1];
  const int wv   = tid >> 6;
  const int lane = tid & 63;
  const int slot = lane >> 4;
  const int c    = lane & 15;
  const bool act = (c < CIN);
  float* Bp = Bl + slot*CSTRIDE;
  __syncthreads();

  if(act){
    for(int e = e0 + slot; e < e1; e += ESW){
      const float4 q  = gw[e];
      const int4   md = gmz[e];
      const float zA = __int_as_float(md.x);
      const float z  = wv ? (1.f - zA) : zA;
      const int   cp = wv ? md.z : md.y;
      float v = feat[(size_t)md.w*CIN + c] * z;
      const int b0 = ( cp        & 255)*CIN + c;
      const int b1 = ((cp >> 8)  & 255)*CIN + c;
      const int b2 = ((cp >> 16) & 255)*CIN + c;
      const int b3 = (((unsigned)cp) >> 24)*CIN + c;
      float o0 = Bp[b0], o1 = Bp[b1], o2 = Bp[b2], o3 = Bp[b3];
      o0 = fmaf(q.x, v, o0); o1 = fmaf(q.y, v, o1);
      o2 = fmaf(q.z, v, o2); o3 = fmaf(q.w, v, o3);
      Bp[b0] = o0; Bp[b1] = o1; Bp[b2] = o2; Bp[b3] = o3;
    }
  }
  __syncthreads();

  float* Bg = B + (size_t)blockIdx.x*BSZ;
  for(int j = tid*4; j < BSZ; j += 512){
    float4 a = *(const float4*)&Bl[j];
    #pragma unroll
    for(int k = 1; k < ESW; ++k){
      const float4 t = *(const float4*)&Bl[k*CSTRIDE + j];
      a.x += t.x; a.y += t.y; a.z += t.z; a.w += t.w;
    }
    *(float4*)&Bg[j] = a;
  }
}

// ---- GEMM, no atomics: P[s][node][64] = sum_{k in split s} A[row,k]*W[k,o]
__global__ __launch_bounds__(256) void k_gemm2(
    const float* __restrict__ A, const float* __restrict__ W,
    float* __restrict__ P, int M, int Kd, int node_base, int ktiles_per)
{
  __shared__ __align__(16) float As[16][68];   // [k][row]
  __shared__ __align__(16) float Ws[16][64];   // [k][col]
  const int tid = threadIdx.x;
  const int mbase = blockIdx.x * 64;
  const int s = blockIdx.y;
  const int kt0 = s * ktiles_per * 16;
  const int kt1 = min(Kd, kt0 + ktiles_per*16);
  const int ty = tid >> 4, tx = tid & 15;
  const int arow = tid >> 2, ako = (tid & 3) * 4;
  const int wk = tid >> 4,  wc = (tid & 15) * 4;

  float acc[4][4];
  #pragma unroll
  for(int i=0;i<4;++i)
    #pragma unroll
    for(int j=0;j<4;++j) acc[i][j] = 0.f;

  for(int kt = kt0; kt < kt1; kt += 16){
    float4 av = make_float4(0.f,0.f,0.f,0.f);
    const int grow = mbase + arow;
    if(grow < M) av = *(const float4*)(A + (size_t)grow*Kd + kt + ako);
    const float4 wv = *(const float4*)(W + (size_t)(kt + wk)*64 + wc);
    As[ako+0][arow]=av.x; As[ako+1][arow]=av.y; As[ako+2][arow]=av.z; As[ako+3][arow]=av.w;
    *(float4*)&Ws[wk][wc] = wv;
    __syncthreads();
    #pragma unroll
    for(int kk = 0; kk < 16; ++kk){
      const float4 a = *(const float4*)&As[kk][ty*4];
      const float4 b = *(const float4*)&Ws[kk][tx*4];
      const float aa[4] = {a.x,a.y,a.z,a.w};
      const float bb[4] = {b.x,b.y,b.z,b.w};
      #pragma unroll
      for(int i=0;i<4;++i)
        #pragma unroll
        for(int j=0;j<4;++j) acc[i][j] = fmaf(aa[i], bb[j], acc[i][j]);
    }
    __syncthreads();
  }

  #pragma unroll
  for(int i=0;i<4;++i){
    const int row = mbase + ty*4 + i;
    if(row < M)
      *(float4*)(P + ((size_t)s*NPTS + node_base + row)*64 + tx*4) = *(float4*)&acc[i][0];
  }
}

// ---- combine partials: x[node*ldout+colofs+o] += sum_s P[s][node][o]
template<int S>
__global__ void k_combine(const float* __restrict__ P, float* __restrict__ x,
                          int ldout, int colofs)
{
  int idx = blockIdx.x*blockDim.x + threadIdx.x;
  if(idx >= NPTS*16) return;
  int node = idx >> 4, c4 = (idx & 15) * 4;
  float4 s = *(const float4*)(P + (size_t)node*64 + c4);
  #pragma unroll
  for(int k=1;k<S;++k){
    float4 t = *(const float4*)(P + ((size_t)k*NPTS + node)*64 + c4);
    s.x+=t.x; s.y+=t.y; s.z+=t.z; s.w+=t.w;
  }
  float* xp = x + (size_t)node*ldout + colofs + c4;
  float4 o = *(float4*)xp;
  o.x+=s.x; o.y+=s.y; o.z+=s.z; o.w+=s.w;
  *(float4*)xp = o;
}

// ---------------- dense paths ----------------
__global__ void k_dense0(const float* __restrict__ f, const float* __restrict__ dW,
                         const float* __restrict__ db, const float* __restrict__ cb0,
                         float* __restrict__ out)
{
  int idx = blockIdx.x*blockDim.x + threadIdx.x;
  if(idx >= NPTS*96) return;
  int i = idx/96, c = idx - i*96;
  if(c < 64){ out[idx] = cb0[c]; return; }
  int o = c - 64;
  float s = db[o];
  const float* row = f + (size_t)i*13;
  #pragma unroll
  for(int j=0;j<13;++j) s = fmaf(row[j], dW[j*32+o], s);
  out[idx] = s;
}

__global__ void k_dense(const float* __restrict__ in, int cin,
                        const float* __restrict__ dW, const float* __restrict__ db,
                        const float* __restrict__ cb, const float* __restrict__ resid,
                        float* __restrict__ out)
{
  int idx = blockIdx.x*blockDim.x + threadIdx.x;
  if(idx >= NPTS*64) return;
  int i = idx >> 6, o = idx & 63;
  float s = db[o] + cb[o];
  if(resid) s += resid[idx];
  const float* row = in + (size_t)i*cin;
  for(int c=0;c<cin;++c) s = fmaf(fmaxf(row[c],0.f), dW[c*64+o], s);
  out[idx] = s;
}

__global__ void k_dense3(const float* __restrict__ x2, const float* __restrict__ dW,
                         const float* __restrict__ db, const float* __restrict__ cb,
                         float* __restrict__ out)
{
  int idx = blockIdx.x*blockDim.x + threadIdx.x;
  if(idx >= NREAL*3) return;
  int i = idx/3, o = idx - i*3;
  float s = db[o] + cb[o];
  const float* row = x2 + (size_t)i*64;
  for(int c=0;c<64;++c) s = fmaf(fmaxf(row[c],0.f), dW[c*3+o], s);
  out[idx] = s * (1.f/128.f);
}

// ---------------- host ----------------
static inline size_t alup(size_t x){ return (x + 255) & ~(size_t)255; }

static inline int calc_rows(size_t bcap, int cin, int want){
  size_t perrow = (size_t)KK * cin * 4;
  size_t r = (perrow > 0) ? bcap / perrow : 0;
  if(r >= (size_t)want) return want;
  r = (r / 128) * 128;
  if(r < 128) r = 128;
  return (int)r;
}

extern "C" void kernel_launch(void* const* d_in, const int* in_sizes, int n_in,
                              void* d_out, int out_size, void* d_ws, size_t ws_size,
                              hipStream_t stream)
{
  const float* pos   = (const float*)d_in[0];
  const float* feats = (const float*)d_in[1];
  const int*   esrc  = (const int*)d_in[2];
  const int*   edst  = (const int*)d_in[3];
  const float* c0w = (const float*)d_in[4];
  const float* c0b = (const float*)d_in[5];
  const float* d0w = (const float*)d_in[6];
  const float* d0b = (const float*)d_in[7];
  const float* c1w = (const float*)d_in[8];
  const float* c1b = (const float*)d_in[9];
  const float* d1w = (const float*)d_in[10];
  const float* d1b = (const float*)d_in[11];
  const float* c2w = (const float*)d_in[12];
  const float* c2b = (const float*)d_in[13];
  const float* d2w = (const float*)d_in[14];
  const float* d2b = (const float*)d_in[15];
  const float* c3w = (const float*)d_in[16];
  const float* c3b = (const float*)d_in[17];
  const float* d3w = (const float*)d_in[18];
  const float* d3b = (const float*)d_in[19];
  float* out = (float*)d_out;

  char* w = (char*)d_ws;
  size_t off = 0;
  float* f  = (float*)(w+off); off += alup((size_t)NPTS*13*4);
  float* x0 = (float*)(w+off); off += alup((size_t)NPTS*96*4);
  float* x1 = (float*)(w+off); off += alup((size_t)NPTS*64*4);
  float* x2 = (float*)(w+off); off += alup((size_t)NPTS*64*4);
  int* row_start = (int*)(w+off); off += alup((size_t)(NPTS+1)*4);
  int* ereal = (int*)(w+off);     off += alup(16);
  float4* gw = (float4*)(w+off);  off += alup((size_t)EPAD*16);    // per-edge xy weights
  int4*  gmz = (int4*)(w+off);    off += alup((size_t)EPAD*16);    // per-edge zA+cells+dst
  float* P  = (float*)(w+off); off += alup((size_t)8*NPTS*64*4);   // split-K partials (S<=8)
  float* B = (float*)(w+off);
  size_t bcap = (ws_size > off) ? (ws_size - off) : 0;

  k_find_ereal<<<1,1,0,stream>>>(edst, ereal);
  k_csr<<<(NPTS+1+255)/256,256,0,stream>>>(esrc, ereal, row_start);
  k_build_f<<<(NPTS*13+255)/256,256,0,stream>>>(feats, f);
  k_geom<<<(EPAD+255)/256,256,0,stream>>>(pos, esrc, edst, gw, gmz);

  // ---- layer 0: x0[:,0:64] = cconv0(f)+c0b ; x0[:,64:96] = f@d0w+d0b  (chunk 8192)
  k_dense0<<<(NPTS*96+255)/256,256,0,stream>>>(f, d0w, d0b, c0b, x0);
  {
    int rows = calc_rows(bcap, 13, 8192);
    for(int base = 0; base < NPTS; base += rows){
      int m = (NPTS - base < rows) ? (NPTS - base) : rows;
      k_scat13<<<m,128,0,stream>>>(f, gw, gmz, row_start, B, base);
      k_gemm2<<<dim3((m+63)/64, 8),256,0,stream>>>(B, c0w, P, m, 832, base, 7);
    }
    k_combine<8><<<(NPTS*16+255)/256,256,0,stream>>>(P, x0, 96, 0);
  }

  // ---- layer 1: x1 = cconv1(relu(x0)) + relu(x0)@d1w + d1b + c1b   (chunk 4096)
  k_dense<<<(NPTS*64+255)/256,256,0,stream>>>(x0, 96, d1w, d1b, c1b, nullptr, x1);
  {
    int rows = calc_rows(bcap, 96, 4096);
    for(int base = 0; base < NPTS; base += rows){
      int m = (NPTS - base < rows) ? (NPTS - base) : rows;
      k_scat96<1><<<m,128,0,stream>>>(x0, gw, gmz, row_start, B, base);
      k_gemm2<<<dim3((m+63)/64, 8),256,0,stream>>>(B, c1w, P, m, 6144, base, 48);
    }
    k_combine<8><<<(NPTS*16+255)/256,256,0,stream>>>(P, x1, 64, 0);
  }

  // ---- layer 2: x2 = cconv2(relu(x1)) + relu(x1)@d2w + d2b + c2b + x1  (chunk 4096)
  k_dense<<<(NPTS*64+255)/256,256,0,stream>>>(x1, 64, d2w, d2b, c2b, x1, x2);
  {
    int rows = calc_rows(bcap, 64, 4096);
    for(int base = 0; base < NPTS; base += rows){
      int m = (NPTS - base < rows) ? (NPTS - base) : rows;
      k_scat64<1,0><<<m,128,0,stream>>>(x1, gw, gmz, row_start, B, base, nullptr, nullptr);
      k_gemm2<<<dim3((m+63)/64, 8),256,0,stream>>>(B, c2w, P, m, 4096, base, 32);
    }
    k_combine<8><<<(NPTS*16+255)/256,256,0,stream>>>(P, x2, 64, 0);
  }

  // ---- layer 3 (fused): out = dense3 part, then scatter adds conv3 GEMV directly
  k_dense3<<<(NREAL*3+255)/256,256,0,stream>>>(x2, d3w, d3b, c3b, out);
  k_scat64<1,1><<<NPTS,128,0,stream>>>(x2, gw, gmz, row_start, nullptr, 0, c3w, out);
}